// Round 9
// baseline (594.311 us; speedup 1.0000x reference)
//
#include <hip/hip_runtime.h>
#include <hip/hip_bf16.h>
#include <cstdint>
#include <cstddef>

#define N_NODES_C 19385
#define N_EDGES_C 1200000
#define GNN_C 256
#define HID_C 512
#define RANK_C 512
#define NCLS_C 3
#define NGENES_C 6640
#define NBLK_C 6
#define B_C 256
#define LN_EPS 1e-5f

// private-histogram geometry: K blocks (one per CU), each owns ~E/K contiguous
// edges, 1024 threads (16 waves/CU) for latency hiding. Packed dual-16b LDS
// bins; per-half chunk count <= 4688 < 65536 and per-half cross-block prefix
// <= node in-degree (<65536) -> no overflow.
#define PH_K 256
#define PH_CHUNK ((N_EDGES_C + PH_K - 1) / PH_K)  // 4688
#define PH_NW ((N_NODES_C + 1) / 2)               // 9693 packed words (38.8 KB LDS)

typedef short bf8v __attribute__((ext_vector_type(8)));
typedef float f4v __attribute__((ext_vector_type(4)));
typedef int i2v __attribute__((ext_vector_type(2)));  // packed (src*GNN, bits(w))

__device__ __forceinline__ float bfu2f(unsigned short u) {
  union { unsigned int i; float f; } c; c.i = ((unsigned)u) << 16; return c.f;
}
__device__ __forceinline__ unsigned short f2bfu(float v) {
  union { float f; unsigned u; } c; c.f = v;
  unsigned r = c.u + 0x7FFFu + ((c.u >> 16) & 1u);
  return (unsigned short)(r >> 16);
}
__device__ __forceinline__ float gelu_tanh(float v) {
  const float x3 = v * v * v;
  return 0.5f * v * (1.f + tanhf(0.7978845608028654f * (v + 0.044715f * x3)));
}

// ---------------- batched fp32 -> bf16 convert ----------------

struct CvtSeg { const float* s; unsigned short* d; long long n; };
struct CvtArgs { CvtSeg seg[2]; int nseg; };

__global__ __launch_bounds__(256) void multicvt_kernel(CvtArgs a) {
  for (int sg = 0; sg < a.nseg; ++sg) {
    const float4* s = reinterpret_cast<const float4*>(a.seg[sg].s);
    unsigned short* d = a.seg[sg].d;
    const long long n4 = a.seg[sg].n >> 2;
    for (long long i = blockIdx.x * 256 + threadIdx.x; i < n4;
         i += (long long)gridDim.x * 256) {
      float4 v = s[i];
      ushort4 o;
      o.x = f2bfu(v.x); o.y = f2bfu(v.y); o.z = f2bfu(v.z); o.w = f2bfu(v.w);
      *reinterpret_cast<ushort4*>(d + i * 4) = o;
    }
  }
}

// ---------------- batched fp32 [R,C] -> bf16 transposed [C,R] ----------------

struct TSeg { const float* s; unsigned short* d; int R, C; };
struct TArgs { TSeg seg[12]; int nseg; };

__global__ __launch_bounds__(256) void multitrans_kernel(TArgs a) {
  __shared__ float tile[32][33];
  const int tx = threadIdx.x & 31;
  const int ty = threadIdx.x >> 5;  // 8 rows/pass
  for (int sg = 0; sg < a.nseg; ++sg) {
    const int R = a.seg[sg].R, C = a.seg[sg].C;
    const int tC = C >> 5;
    const int nt = (R >> 5) * tC;
    const float* src = a.seg[sg].s;
    unsigned short* dst = a.seg[sg].d;
    for (int tid = blockIdx.x; tid < nt; tid += gridDim.x) {
      const int tr = tid / tC, tc = tid - tr * tC;
      const int r0 = tr * 32, c0 = tc * 32;
      __syncthreads();
#pragma unroll
      for (int j = 0; j < 32; j += 8)
        tile[ty + j][tx] = src[(size_t)(r0 + ty + j) * C + c0 + tx];
      __syncthreads();
#pragma unroll
      for (int j = 0; j < 32; j += 8)
        dst[(size_t)(c0 + ty + j) * R + r0 + tx] = f2bfu(tile[tx][ty + j]);
    }
  }
}

// ---------------- frontier marking (fused zero+set: no memsets, no races) ----

__global__ __launch_bounds__(256) void initmark_kernel(const int* __restrict__ node_idx,
                                                       int* __restrict__ selbm,
                                                       int* __restrict__ needed) {
  __shared__ int sel[B_C];
  sel[threadIdx.x] = max(node_idx[threadIdx.x], 0);  // 256 threads == B_C
  __syncthreads();
  for (int i = blockIdx.x * 256 + threadIdx.x; i < N_NODES_C;
       i += gridDim.x * 256) {
    int m = 0;
#pragma unroll 16
    for (int j = 0; j < B_C; ++j) m |= (sel[j] == i);
    selbm[i] = m;
    needed[i] = m;
  }
}

// per-block private LDS histogram (packed 2x16b) + frontier source marking.
// ZERO global atomics: each block flushes its bins with plain coalesced stores.
__global__ __launch_bounds__(1024) void privhist_kernel(const int* __restrict__ src,
                                                        const int* __restrict__ dst,
                                                        const int* __restrict__ selbm,
                                                        int* __restrict__ needed,
                                                        unsigned int* __restrict__ cntp) {
  __shared__ unsigned int bins[PH_NW];
  const int t = threadIdx.x;
  for (int w = t; w < PH_NW; w += 1024) bins[w] = 0u;
  __syncthreads();
  const int base = blockIdx.x * PH_CHUNK;
  const int end = min(base + PH_CHUNK, N_EDGES_C);
#pragma unroll 2
  for (int i = base + t; i < end; i += 1024) {
    const int d = dst[i];
    atomicAdd(&bins[d >> 1], 1u << ((d & 1) * 16));
    if (selbm[d]) needed[src[i]] = 1;
  }
  __syncthreads();
  unsigned int* out = cntp + (size_t)blockIdx.x * PH_NW;
  for (int w = t; w < PH_NW; w += 1024) out[w] = bins[w];
}

// sum the PH_K packed private histograms -> per-node degree (int), and
// REPLACE cntp[k][w] in place with the packed EXCLUSIVE cross-block prefix.
__global__ __launch_bounds__(256) void redhist_kernel(unsigned int* __restrict__ cntp,
                                                      int* __restrict__ cnt) {
  const int w = blockIdx.x * 256 + threadIdx.x;
  if (w >= PH_NW) return;
  unsigned int lo = 0, hi = 0;
#pragma unroll 4
  for (int k = 0; k < PH_K; ++k) {
    const size_t idx = (size_t)k * PH_NW + w;
    const unsigned int u = cntp[idx];
    cntp[idx] = lo | (hi << 16);
    lo += u & 0xFFFFu;
    hi += u >> 16;
  }
  cnt[2 * w] = (int)lo;
  if (2 * w + 1 < N_NODES_C) cnt[2 * w + 1] = (int)hi;
}

__global__ __launch_bounds__(1024) void scan_kernel(const int* __restrict__ cnt,
                                                    int* __restrict__ off, int n) {
  __shared__ int sums[1024];
  const int t = threadIdx.x;
  const int CH = (n + 1023) >> 10;
  const int base = t * CH;
  int s = 0;
  for (int i = 0; i < CH; ++i) {
    int idx = base + i;
    if (idx < n) s += cnt[idx];
  }
  sums[t] = s;
  __syncthreads();
  for (int d = 1; d < 1024; d <<= 1) {
    int v = (t >= d) ? sums[t - d] : 0;
    __syncthreads();
    sums[t] += v;
    __syncthreads();
  }
  int run = (t == 0) ? 0 : sums[t - 1];
  for (int i = 0; i < CH; ++i) {
    int idx = base + i;
    if (idx < n) { off[idx] = run; run += cnt[idx]; }
  }
  if (t == 0) off[n] = sums[1023];
}

// deterministic-slot scatter, ZERO global atomics (prefix-seeded LDS ranks).
__global__ __launch_bounds__(1024) void fill_kernel(const int* __restrict__ src,
                                                    const int* __restrict__ dst,
                                                    const float* __restrict__ ew,
                                                    const int* __restrict__ off,
                                                    const unsigned int* __restrict__ cntp,
                                                    const int* __restrict__ needed,
                                                    i2v* __restrict__ ep) {
  __shared__ unsigned int bins[PH_NW];
  const int t = threadIdx.x;
  const unsigned int* myp = cntp + (size_t)blockIdx.x * PH_NW;
  for (int w = t; w < PH_NW; w += 1024) bins[w] = myp[w];
  __syncthreads();
  const int base = blockIdx.x * PH_CHUNK;
  const int end = min(base + PH_CHUNK, N_EDGES_C);
#pragma unroll 2
  for (int i = base + t; i < end; i += 1024) {
    const int d = dst[i];
    if (!needed[d]) continue;
    const int sh = (d & 1) * 16;
    const unsigned int old = atomicAdd(&bins[d >> 1], 1u << sh);
    const int rank = (int)((old >> sh) & 0xFFFFu);
    i2v e;
    e[0] = src[i] * GNN_C;
    e[1] = __float_as_int(ew[i]);
    ep[off[d] + rank] = e;
  }
}

// ---------------- edge aggregation ----------------

__global__ __launch_bounds__(256) void agg_full_kernel(const i2v* __restrict__ ep,
                                                       const int* __restrict__ off,
                                                       const int* __restrict__ needed,
                                                       const unsigned short* __restrict__ x,
                                                       unsigned short* __restrict__ aggbf) {
  const int n = blockIdx.x;
  if (!needed[n]) return;  // uniform: whole block exits together
  __shared__ f4v red[4][64];
  const int t = threadIdx.x;
  const int w = __builtin_amdgcn_readfirstlane(t >> 6);
  const int lane = t & 63;
  const int s0 = off[n];
  const int c = off[n + 1] - s0;
  const int q0 = s0 + ((c * w) >> 2);
  const int q1 = s0 + ((c * (w + 1)) >> 2);
  float a0 = 0.f, a1 = 0.f, a2 = 0.f, a3 = 0.f;
  const unsigned short* xl = x + 4 * lane;
#pragma unroll 4
  for (int p = q0; p < q1; ++p) {
    const i2v e = ep[p];  // wave-uniform -> s_load_dwordx2
    const int s = e[0];
    const float wg = __int_as_float(e[1]);
    const ushort4 v = *reinterpret_cast<const ushort4*>(xl + s);
    a0 = fmaf(bfu2f(v.x), wg, a0);
    a1 = fmaf(bfu2f(v.y), wg, a1);
    a2 = fmaf(bfu2f(v.z), wg, a2);
    a3 = fmaf(bfu2f(v.w), wg, a3);
  }
  f4v av; av[0] = a0; av[1] = a1; av[2] = a2; av[3] = a3;
  red[w][lane] = av;
  __syncthreads();
  const float* rf = reinterpret_cast<const float*>(red);
  const float sum = rf[t] + rf[256 + t] + rf[512 + t] + rf[768 + t];
  aggbf[(size_t)n * GNN_C + t] = f2bfu(sum);
}

__global__ __launch_bounds__(256) void agg_sel_kernel(const int* __restrict__ node_idx,
                                                      const i2v* __restrict__ ep,
                                                      const int* __restrict__ off,
                                                      const float* __restrict__ x,
                                                      unsigned short* __restrict__ aggbf) {
  __shared__ f4v red[4][64];
  const int b = blockIdx.x;
  const int t = threadIdx.x;
  const int n = max(node_idx[b], 0);
  const int w = __builtin_amdgcn_readfirstlane(t >> 6);
  const int lane = t & 63;
  const int s0 = off[n];
  const int c = off[n + 1] - s0;
  const int q0 = s0 + ((c * w) >> 2);
  const int q1 = s0 + ((c * (w + 1)) >> 2);
  float a0 = 0.f, a1 = 0.f, a2 = 0.f, a3 = 0.f;
  const float* xl = x + 4 * lane;
#pragma unroll 2
  for (int p = q0; p < q1; ++p) {
    const i2v e = ep[p];
    const int s = e[0];
    const float wg = __int_as_float(e[1]);
    const f4v v = *reinterpret_cast<const f4v*>(xl + s);
    a0 = fmaf(v[0], wg, a0);
    a1 = fmaf(v[1], wg, a1);
    a2 = fmaf(v[2], wg, a2);
    a3 = fmaf(v[3], wg, a3);
  }
  f4v av; av[0] = a0; av[1] = a1; av[2] = a2; av[3] = a3;
  red[w][lane] = av;
  __syncthreads();
  const float* rf = reinterpret_cast<const float*>(red);
  const float sum = rf[t] + rf[256 + t] + rf[512 + t] + rf[768 + t];
  aggbf[(size_t)b * GNN_C + t] = f2bfu(sum);
}

// ---------------- MFMA bf16 GEMM 128x128, transB only ----------------

#define MBK 32
#define MLDW 40

__global__ __launch_bounds__(256) void mgemm_kernel(const unsigned short* __restrict__ A,
                                                    const unsigned short* __restrict__ Bt,
                                                    const float* __restrict__ bias,
                                                    float* __restrict__ C,
                                                    int M, int N, int K) {
  __shared__ unsigned short As[128][MLDW];
  __shared__ unsigned short Bs[128][MLDW];
  const int t = threadIdx.x;
  const int lane = t & 63;
  const int wave = t >> 6;
  const int r0 = blockIdx.x * 128;
  const int c0 = blockIdx.y * 128;
  const int wm = (wave >> 1) * 64;
  const int wn = (wave & 1) * 64;
  const int lm = lane & 15;
  const int lq = lane >> 4;

  f4v acc[4][4];
  for (int i = 0; i < 4; ++i)
    for (int j = 0; j < 4; ++j)
      for (int r = 0; r < 4; ++r) acc[i][j][r] = 0.f;

  const int row = t >> 1;
  const int kof = (t & 1) * 16;
  for (int k0 = 0; k0 < K; k0 += MBK) {
    {
      const int gr = r0 + row;
      uint4 u0 = make_uint4(0, 0, 0, 0), u1 = u0;
      if (gr < M) {
        const uint4* p = reinterpret_cast<const uint4*>(A + (size_t)gr * K + k0 + kof);
        u0 = p[0]; u1 = p[1];
      }
      *reinterpret_cast<uint4*>(&As[row][kof]) = u0;
      *reinterpret_cast<uint4*>(&As[row][kof + 8]) = u1;
    }
    {
      const int gn = c0 + row;
      uint4 u0 = make_uint4(0, 0, 0, 0), u1 = u0;
      if (gn < N) {
        const uint4* p = reinterpret_cast<const uint4*>(Bt + (size_t)gn * K + k0 + kof);
        u0 = p[0]; u1 = p[1];
      }
      *reinterpret_cast<uint4*>(&Bs[row][kof]) = u0;
      *reinterpret_cast<uint4*>(&Bs[row][kof + 8]) = u1;
    }
    __syncthreads();

    bf8v a[4], b[4];
#pragma unroll
    for (int i = 0; i < 4; ++i)
      a[i] = *reinterpret_cast<const bf8v*>(&As[wm + i * 16 + lm][lq * 8]);
#pragma unroll
    for (int j = 0; j < 4; ++j)
      b[j] = *reinterpret_cast<const bf8v*>(&Bs[wn + j * 16 + lm][lq * 8]);
#pragma unroll
    for (int i = 0; i < 4; ++i)
#pragma unroll
      for (int j = 0; j < 4; ++j)
        acc[i][j] = __builtin_amdgcn_mfma_f32_16x16x32_bf16(a[i], b[j], acc[i][j], 0, 0, 0);
    __syncthreads();
  }

  for (int ti = 0; ti < 4; ++ti) {
    for (int tj = 0; tj < 4; ++tj) {
      const int col = c0 + wn + tj * 16 + lm;
      if (col >= N) continue;
      const float bv = bias ? bias[col] : 0.f;
      for (int r = 0; r < 4; ++r) {
        const int row2 = r0 + wm + ti * 16 + lq * 4 + r;
        if (row2 < M) C[(size_t)row2 * N + col] = acc[ti][tj][r] + bv;
      }
    }
  }
}

// ---------------- MFMA bf16 GEMM 64x64, transB, fused epilogue ----------------

__global__ __launch_bounds__(256) void mgemm64_kernel(const unsigned short* __restrict__ A,
                                                      const unsigned short* __restrict__ Bt,
                                                      const float* __restrict__ bias,
                                                      float* outF, unsigned short* outB,
                                                      int M, int N, int K, int doGelu) {
  __shared__ unsigned short As[64][MLDW];
  __shared__ unsigned short Bs[64][MLDW];
  const int t = threadIdx.x;
  const int lane = t & 63;
  const int wave = t >> 6;
  const int r0 = blockIdx.x * 64;
  const int c0 = blockIdx.y * 64;
  const int wm = (wave >> 1) * 32;
  const int wn = (wave & 1) * 32;
  const int lm = lane & 15;
  const int lq = lane >> 4;

  f4v acc[2][2];
  for (int i = 0; i < 2; ++i)
    for (int j = 0; j < 2; ++j)
      for (int r = 0; r < 4; ++r) acc[i][j][r] = 0.f;

  const int row = t >> 2;
  const int kof = (t & 3) * 8;
  for (int k0 = 0; k0 < K; k0 += MBK) {
    *reinterpret_cast<uint4*>(&As[row][kof]) =
        *reinterpret_cast<const uint4*>(A + (size_t)(r0 + row) * K + k0 + kof);
    *reinterpret_cast<uint4*>(&Bs[row][kof]) =
        *reinterpret_cast<const uint4*>(Bt + (size_t)(c0 + row) * K + k0 + kof);
    __syncthreads();
    bf8v a[2], b[2];
#pragma unroll
    for (int i = 0; i < 2; ++i)
      a[i] = *reinterpret_cast<const bf8v*>(&As[wm + i * 16 + lm][lq * 8]);
#pragma unroll
    for (int j = 0; j < 2; ++j)
      b[j] = *reinterpret_cast<const bf8v*>(&Bs[wn + j * 16 + lm][lq * 8]);
#pragma unroll
    for (int i = 0; i < 2; ++i)
#pragma unroll
      for (int j = 0; j < 2; ++j)
        acc[i][j] = __builtin_amdgcn_mfma_f32_16x16x32_bf16(a[i], b[j], acc[i][j], 0, 0, 0);
    __syncthreads();
  }

  for (int ti = 0; ti < 2; ++ti) {
    for (int tj = 0; tj < 2; ++tj) {
      const int col = c0 + wn + tj * 16 + lm;
      const float bv = bias ? bias[col] : 0.f;
      for (int r = 0; r < 4; ++r) {
        const int row2 = r0 + wm + ti * 16 + lq * 4 + r;
        float v = acc[ti][tj][r] + bv;
        if (doGelu) v = gelu_tanh(v);
        if (outF) outF[(size_t)row2 * N + col] = v;
        else outB[(size_t)row2 * N + col] = f2bfu(v);
      }
    }
  }
}

// split-K variant: grid.z slices write raw fp32 partials part[z][M][N]
__global__ __launch_bounds__(256) void skmgemm64_kernel(const unsigned short* __restrict__ A,
                                                        const unsigned short* __restrict__ Bt,
                                                        float* __restrict__ part,
                                                        int M, int N, int K, int kc) {
  __shared__ unsigned short As[64][MLDW];
  __shared__ unsigned short Bs[64][MLDW];
  const int t = threadIdx.x;
  const int lane = t & 63;
  const int wave = t >> 6;
  const int r0 = blockIdx.x * 64;
  const int c0 = blockIdx.y * 64;
  const int kBeg = blockIdx.z * kc;
  const int kEnd = kBeg + kc;
  const int wm = (wave >> 1) * 32;
  const int wn = (wave & 1) * 32;
  const int lm = lane & 15;
  const int lq = lane >> 4;

  f4v acc[2][2];
  for (int i = 0; i < 2; ++i)
    for (int j = 0; j < 2; ++j)
      for (int r = 0; r < 4; ++r) acc[i][j][r] = 0.f;

  const int row = t >> 2;
  const int kof = (t & 3) * 8;
  for (int k0 = kBeg; k0 < kEnd; k0 += MBK) {
    *reinterpret_cast<uint4*>(&As[row][kof]) =
        *reinterpret_cast<const uint4*>(A + (size_t)(r0 + row) * K + k0 + kof);
    *reinterpret_cast<uint4*>(&Bs[row][kof]) =
        *reinterpret_cast<const uint4*>(Bt + (size_t)(c0 + row) * K + k0 + kof);
    __syncthreads();
    bf8v a[2], b[2];
#pragma unroll
    for (int i = 0; i < 2; ++i)
      a[i] = *reinterpret_cast<const bf8v*>(&As[wm + i * 16 + lm][lq * 8]);
#pragma unroll
    for (int j = 0; j < 2; ++j)
      b[j] = *reinterpret_cast<const bf8v*>(&Bs[wn + j * 16 + lm][lq * 8]);
#pragma unroll
    for (int i = 0; i < 2; ++i)
#pragma unroll
      for (int j = 0; j < 2; ++j)
        acc[i][j] = __builtin_amdgcn_mfma_f32_16x16x32_bf16(a[i], b[j], acc[i][j], 0, 0, 0);
    __syncthreads();
  }

  float* out = part + (size_t)blockIdx.z * M * N;
  for (int ti = 0; ti < 2; ++ti)
    for (int tj = 0; tj < 2; ++tj) {
      const int col = c0 + wn + tj * 16 + lm;
      for (int r = 0; r < 4; ++r) {
        const int row2 = r0 + wm + ti * 16 + lq * 4 + r;
        out[(size_t)row2 * N + col] = acc[ti][tj][r];
      }
    }
}

// ---------------- fused conv6 GEMM + LayerNorm ----------------
// 64-row x 256-col blocks, 8 waves (512 thr); wave w owns cols [w*32,(w+1)*32).
// Full output row lives in one block -> LN/ReLU/+frozen fuse in epilogue.
// conv6: yx[row] = frozen[row] + relu(LN(agg@W6 + b6)) for needed rows only.
__global__ __launch_bounds__(512) void gemmln6_kernel(const unsigned short* __restrict__ A,
                                                      const unsigned short* __restrict__ Bt,
                                                      const float* __restrict__ bias,
                                                      const float* __restrict__ g,
                                                      const float* __restrict__ b,
                                                      const float* __restrict__ frozen,
                                                      const int* __restrict__ needed,
                                                      float* __restrict__ yx, int M) {
  __shared__ unsigned short As[64][MLDW];
  __shared__ unsigned short Bs[256][MLDW];
  __shared__ float rs[64][8];
  const int t = threadIdx.x;
  const int lane = t & 63;
  const int wave = t >> 6;  // 0..7
  const int r0 = blockIdx.x * 64;
  const int lm = lane & 15, lq = lane >> 4;

  f4v acc[4][2];
#pragma unroll
  for (int i = 0; i < 4; ++i)
#pragma unroll
    for (int j = 0; j < 2; ++j)
#pragma unroll
      for (int r = 0; r < 4; ++r) acc[i][j][r] = 0.f;

  const int arow = t >> 3, akof = (t & 7) * 4;   // 64 rows x 32k / 512thr = ushort4
  const int brow = t >> 1, bkof = (t & 1) * 16;  // 256 rows x 32k / 512thr = 2x uint4
  for (int k0 = 0; k0 < GNN_C; k0 += MBK) {
    ushort4 u = make_ushort4(0, 0, 0, 0);
    const int gr = r0 + arow;
    if (gr < M) u = *reinterpret_cast<const ushort4*>(A + (size_t)gr * GNN_C + k0 + akof);
    *reinterpret_cast<ushort4*>(&As[arow][akof]) = u;
    const uint4* p = reinterpret_cast<const uint4*>(Bt + (size_t)brow * GNN_C + k0 + bkof);
    *reinterpret_cast<uint4*>(&Bs[brow][bkof]) = p[0];
    *reinterpret_cast<uint4*>(&Bs[brow][bkof + 8]) = p[1];
    __syncthreads();
    bf8v a[4], bf[2];
#pragma unroll
    for (int ti = 0; ti < 4; ++ti)
      a[ti] = *reinterpret_cast<const bf8v*>(&As[ti * 16 + lm][lq * 8]);
#pragma unroll
    for (int tj = 0; tj < 2; ++tj)
      bf[tj] = *reinterpret_cast<const bf8v*>(&Bs[wave * 32 + tj * 16 + lm][lq * 8]);
#pragma unroll
    for (int ti = 0; ti < 4; ++ti)
#pragma unroll
      for (int tj = 0; tj < 2; ++tj)
        acc[ti][tj] = __builtin_amdgcn_mfma_f32_16x16x32_bf16(a[ti], bf[tj], acc[ti][tj], 0, 0, 0);
    __syncthreads();
  }

  // + bias (pre-LN, matches reference y6 = agg@W + b)
  const int c0 = wave * 32 + lm, c1 = c0 + 16;
  const float b0 = bias[c0], b1 = bias[c1];
#pragma unroll
  for (int ti = 0; ti < 4; ++ti)
#pragma unroll
    for (int r = 0; r < 4; ++r) { acc[ti][0][r] += b0; acc[ti][1][r] += b1; }

  // mean
  float m[4][4];
#pragma unroll
  for (int ti = 0; ti < 4; ++ti)
#pragma unroll
    for (int r = 0; r < 4; ++r) {
      float s = acc[ti][0][r] + acc[ti][1][r];
      for (int o = 1; o < 16; o <<= 1) s += __shfl_xor(s, o, 64);
      if (lm == 0) rs[ti * 16 + lq * 4 + r][wave] = s;
    }
  __syncthreads();
#pragma unroll
  for (int ti = 0; ti < 4; ++ti)
#pragma unroll
    for (int r = 0; r < 4; ++r) {
      const int row = ti * 16 + lq * 4 + r;
      float s = 0.f;
#pragma unroll
      for (int w2 = 0; w2 < 8; ++w2) s += rs[row][w2];
      m[ti][r] = s * (1.f / GNN_C);
    }
  __syncthreads();
  // variance
  float iv[4][4];
#pragma unroll
  for (int ti = 0; ti < 4; ++ti)
#pragma unroll
    for (int r = 0; r < 4; ++r) {
      const float d0 = acc[ti][0][r] - m[ti][r];
      const float d1 = acc[ti][1][r] - m[ti][r];
      float s = d0 * d0 + d1 * d1;
      for (int o = 1; o < 16; o <<= 1) s += __shfl_xor(s, o, 64);
      if (lm == 0) rs[ti * 16 + lq * 4 + r][wave] = s;
    }
  __syncthreads();
#pragma unroll
  for (int ti = 0; ti < 4; ++ti)
#pragma unroll
    for (int r = 0; r < 4; ++r) {
      const int row = ti * 16 + lq * 4 + r;
      float s = 0.f;
#pragma unroll
      for (int w2 = 0; w2 < 8; ++w2) s += rs[row][w2];
      iv[ti][r] = rsqrtf(s * (1.f / GNN_C) + LN_EPS);
    }

  const float g0 = g[c0], g1 = g[c1], bb0 = b[c0], bb1 = b[c1];
#pragma unroll
  for (int ti = 0; ti < 4; ++ti)
#pragma unroll
    for (int r = 0; r < 4; ++r) {
      const int grow = r0 + ti * 16 + lq * 4 + r;
      if (grow < M && needed[grow]) {
        const size_t base = (size_t)grow * GNN_C;
        const float x0 = fmaxf((acc[ti][0][r] - m[ti][r]) * iv[ti][r] * g0 + bb0, 0.f);
        const float x1 = fmaxf((acc[ti][1][r] - m[ti][r]) * iv[ti][r] * g1 + bb1, 0.f);
        yx[base + c0] = frozen[base + c0] + x0;
        yx[base + c1] = frozen[base + c1] + x1;
      }
    }
}

// ---------------- LN family (head path, round-6 form) ----------------

__global__ __launch_bounds__(256) void postconv7_kernel(const float* __restrict__ y,
                                                        const float* __restrict__ g,
                                                        const float* __restrict__ b,
                                                        const int* __restrict__ idx,
                                                        const float* __restrict__ x1f,
                                                        unsigned short* __restrict__ out) {
  __shared__ float sb[4];
  const int bi = blockIdx.x, t = threadIdx.x;
  const int n = max(idx[bi], 0);
  const float v = y[(size_t)bi * GNN_C + t];
  float s = v;
  for (int o = 32; o; o >>= 1) s += __shfl_down(s, o, 64);
  if ((t & 63) == 0) sb[t >> 6] = s;
  __syncthreads();
  const float m = (sb[0] + sb[1] + sb[2] + sb[3]) * (1.f / GNN_C);
  __syncthreads();
  const float d = v - m;
  s = d * d;
  for (int o = 32; o; o >>= 1) s += __shfl_down(s, o, 64);
  if ((t & 63) == 0) sb[t >> 6] = s;
  __syncthreads();
  const float rs = rsqrtf((sb[0] + sb[1] + sb[2] + sb[3]) * (1.f / GNN_C) + LN_EPS);
  const float xn = d * rs * g[t] + b[t];
  out[(size_t)bi * GNN_C + t] = f2bfu(x1f[(size_t)n * GNN_C + t] + fmaxf(xn, 0.f));
}

__global__ __launch_bounds__(256) void h0ln_kernel(const float* __restrict__ ne,
                                                   const int* __restrict__ idx,
                                                   const float* __restrict__ oov,
                                                   const float* __restrict__ g,
                                                   const float* __restrict__ b,
                                                   unsigned short* __restrict__ out) {
  __shared__ float sb[4];
  const int bi = blockIdx.x, t = threadIdx.x;
  const float v = (idx[bi] >= 0) ? ne[(size_t)bi * GNN_C + t] : oov[t];
  float s = v;
  for (int o = 32; o; o >>= 1) s += __shfl_down(s, o, 64);
  if ((t & 63) == 0) sb[t >> 6] = s;
  __syncthreads();
  const float m = (sb[0] + sb[1] + sb[2] + sb[3]) * (1.f / GNN_C);
  __syncthreads();
  const float d = v - m;
  s = d * d;
  for (int o = 32; o; o >>= 1) s += __shfl_down(s, o, 64);
  if ((t & 63) == 0) sb[t >> 6] = s;
  __syncthreads();
  const float rs = rsqrtf((sb[0] + sb[1] + sb[2] + sb[3]) * (1.f / GNN_C) + LN_EPS);
  out[(size_t)bi * GNN_C + t] = f2bfu(d * rs * g[t] + b[t]);
}

// plain LN over 512-rows of h -> bf16
__global__ __launch_bounds__(256) void lnbf_kernel(const float* __restrict__ in,
                                                   const float* __restrict__ g,
                                                   const float* __restrict__ b,
                                                   unsigned short* __restrict__ out) {
  __shared__ float sb[4];
  const int r = blockIdx.x, t = threadIdx.x;
  const float v0 = in[(size_t)r * HID_C + t];
  const float v1 = in[(size_t)r * HID_C + t + 256];
  float s = v0 + v1;
  for (int o = 32; o; o >>= 1) s += __shfl_down(s, o, 64);
  if ((t & 63) == 0) sb[t >> 6] = s;
  __syncthreads();
  const float m = (sb[0] + sb[1] + sb[2] + sb[3]) * (1.f / HID_C);
  __syncthreads();
  const float d0 = v0 - m, d1 = v1 - m;
  s = d0 * d0 + d1 * d1;
  for (int o = 32; o; o >>= 1) s += __shfl_down(s, o, 64);
  if ((t & 63) == 0) sb[t >> 6] = s;
  __syncthreads();
  const float rs = rsqrtf((sb[0] + sb[1] + sb[2] + sb[3]) * (1.f / HID_C) + LN_EPS);
  out[(size_t)r * HID_C + t] = f2bfu(d0 * rs * g[t] + b[t]);
  out[(size_t)r * HID_C + t + 256] = f2bfu(d1 * rs * g[t + 256] + b[t + 256]);
}

// combine split-K partials + bias + residual into h, then LN (next gamma/beta) -> bf16
__global__ __launch_bounds__(256) void combln_kernel(const float* __restrict__ part,
                                                     float* __restrict__ h,
                                                     const float* __restrict__ b2,
                                                     const float* __restrict__ g,
                                                     const float* __restrict__ b,
                                                     unsigned short* __restrict__ out) {
  __shared__ float sb[4];
  const int r = blockIdx.x, t = threadIdx.x;
  const int MN = B_C * HID_C;
  const size_t o0 = (size_t)r * HID_C + t;
  const size_t o1 = o0 + 256;
  float v0 = h[o0] + b2[t] + part[o0] + part[MN + o0] + part[2 * MN + o0] + part[3 * MN + o0];
  float v1 = h[o1] + b2[t + 256] + part[o1] + part[MN + o1] + part[2 * MN + o1] + part[3 * MN + o1];
  h[o0] = v0;
  h[o1] = v1;
  float s = v0 + v1;
  for (int o = 32; o; o >>= 1) s += __shfl_down(s, o, 64);
  if ((t & 63) == 0) sb[t >> 6] = s;
  __syncthreads();
  const float m = (sb[0] + sb[1] + sb[2] + sb[3]) * (1.f / HID_C);
  __syncthreads();
  const float d0 = v0 - m, d1 = v1 - m;
  s = d0 * d0 + d1 * d1;
  for (int o = 32; o; o >>= 1) s += __shfl_down(s, o, 64);
  if ((t & 63) == 0) sb[t >> 6] = s;
  __syncthreads();
  const float rsq = rsqrtf((sb[0] + sb[1] + sb[2] + sb[3]) * (1.f / HID_C) + LN_EPS);
  out[o0] = f2bfu(d0 * rsq * g[t] + b[t]);
  out[o1] = f2bfu(d1 * rsq * g[t + 256] + b[t + 256]);
}

// ---------------- host ----------------

extern "C" void kernel_launch(void* const* d_in, const int* in_sizes, int n_in,
                              void* d_out, int out_size, void* d_ws, size_t ws_size,
                              hipStream_t stream) {
  const int* node_idx = (const int*)d_in[0];
  const int* e_src = (const int*)d_in[1];
  const int* e_dst = e_src + N_EDGES_C;
  const float* ew = (const float*)d_in[2];
  const float* frozen = (const float*)d_in[3];
  const float* W6 = (const float*)d_in[4];
  const float* b6 = (const float*)d_in[5];
  const float* g6 = (const float*)d_in[6];
  const float* bl6 = (const float*)d_in[7];
  const float* W7 = (const float*)d_in[8];
  const float* b7 = (const float*)d_in[9];
  const float* g7 = (const float*)d_in[10];
  const float* bl7 = (const float*)d_in[11];
  const float* postW = (const float*)d_in[12];
  const float* postb = (const float*)d_in[13];
  const float* oov = (const float*)d_in[14];
  const float* ing = (const float*)d_in[15];
  const float* inb = (const float*)d_in[16];
  const float* projW = (const float*)d_in[17];
  const float* projb = (const float*)d_in[18];
  const float* rbg = (const float*)d_in[19];
  const float* rbb = (const float*)d_in[20];
  const float* rbW1 = (const float*)d_in[21];
  const float* rbb1 = (const float*)d_in[22];
  const float* rbW2 = (const float*)d_in[23];
  const float* rbb2 = (const float*)d_in[24];
  const float* outg = (const float*)d_in[25];
  const float* outb = (const float*)d_in[26];
  const float* bilW = (const float*)d_in[27];
  const float* bilb = (const float*)d_in[28];
  const float* gene = (const float*)d_in[29];
  (void)in_sizes; (void)n_in; (void)out_size; (void)ws_size;

  char* ws = (char*)d_ws;
  size_t o = 0;
  auto alloc = [&](size_t bytes) -> char* {
    char* p = ws + o;
    o += (bytes + 255) & ~(size_t)255;
    return p;
  };
  int* cnt = (int*)alloc((size_t)N_NODES_C * 4);
  int* off = (int*)alloc((size_t)(N_NODES_C + 1) * 4);
  int* needed = (int*)alloc((size_t)N_NODES_C * 4);
  int* selbm = (int*)alloc((size_t)N_NODES_C * 4);
  unsigned int* cntp = (unsigned int*)alloc((size_t)PH_K * PH_NW * 4);
  i2v* ep = (i2v*)alloc((size_t)N_EDGES_C * 8);
  unsigned short* frozbf = (unsigned short*)alloc((size_t)N_NODES_C * GNN_C * 2);
  // aggregion: agg6bf (9.93 MB, dead after conv6 GEMM) then rbW1t (12.58 MB, phase B)
  char* aggregion = alloc((size_t)NBLK_C * HID_C * 4 * HID_C * 2);
  unsigned short* w6t = (unsigned short*)alloc((size_t)GNN_C * GNN_C * 2);
  unsigned short* w7t = (unsigned short*)alloc((size_t)GNN_C * GNN_C * 2);
  unsigned short* postWt = (unsigned short*)alloc((size_t)GNN_C * GNN_C * 2);
  unsigned short* projWt = (unsigned short*)alloc((size_t)HID_C * GNN_C * 2);
  unsigned short* bilWt = (unsigned short*)alloc((size_t)NCLS_C * RANK_C * HID_C * 2);
  float* yx = (float*)alloc((size_t)N_NODES_C * GNN_C * 4);  // x1 fp32 (gated write)
  unsigned short* rbW2t = (unsigned short*)alloc((size_t)NBLK_C * 4 * HID_C * HID_C * 2);
  float* part = (float*)alloc((size_t)4 * B_C * HID_C * 4);
  unsigned short* agg7bf = (unsigned short*)alloc((size_t)B_C * GNN_C * 2);
  float* y7b = (float*)alloc((size_t)B_C * GNN_C * 4);
  unsigned short* x2bf = (unsigned short*)alloc((size_t)B_C * GNN_C * 2);
  float* nemb = (float*)alloc((size_t)B_C * GNN_C * 4);
  unsigned short* h0lbf = (unsigned short*)alloc((size_t)B_C * GNN_C * 2);
  float* h = (float*)alloc((size_t)B_C * HID_C * 4);
  unsigned short* tbf = (unsigned short*)alloc((size_t)B_C * HID_C * 2);
  unsigned short* ubf = (unsigned short*)alloc((size_t)B_C * 4 * HID_C * 2);
  unsigned short* pertbf = (unsigned short*)alloc((size_t)B_C * NCLS_C * RANK_C * 2);

  unsigned short* agg6bf = (unsigned short*)aggregion;
  unsigned short* rbW1t = (unsigned short*)aggregion;
  unsigned short* genebf = frozbf;  // frozbf dead after agg_full

  // frontier marking (fused zero+set) + privatized histogram + prefix
  // write-back, then deterministic-slot fill (zero global atomics)
  initmark_kernel<<<80, 256, 0, stream>>>(node_idx, selbm, needed);
  privhist_kernel<<<PH_K, 1024, 0, stream>>>(e_src, e_dst, selbm, needed, cntp);
  redhist_kernel<<<(PH_NW + 255) / 256, 256, 0, stream>>>(cntp, cnt);
  scan_kernel<<<1, 1024, 0, stream>>>(cnt, off, N_NODES_C);
  fill_kernel<<<PH_K, 1024, 0, stream>>>(e_src, e_dst, ew, off, cntp, needed, ep);

  // phase A: frozen convert + small weight transposes
  {
    CvtArgs a;
    a.seg[0] = {frozen, frozbf, (long long)N_NODES_C * GNN_C};
    a.nseg = 1;
    multicvt_kernel<<<512, 256, 0, stream>>>(a);
  }
  {
    TArgs a;
    a.seg[0] = {W6, w6t, GNN_C, GNN_C};
    a.seg[1] = {W7, w7t, GNN_C, GNN_C};
    a.seg[2] = {postW, postWt, GNN_C, GNN_C};
    a.seg[3] = {projW, projWt, GNN_C, HID_C};
    a.seg[4] = {bilW, bilWt, HID_C, NCLS_C * RANK_C};
    a.nseg = 5;
    multitrans_kernel<<<512, 256, 0, stream>>>(a);
  }

  // conv6 trunk: aggregate then fused GEMM + LN + ReLU + residual (gated)
  agg_full_kernel<<<N_NODES_C, 256, 0, stream>>>(ep, off, needed, frozbf, agg6bf);
  gemmln6_kernel<<<(N_NODES_C + 63) / 64, 512, 0, stream>>>(agg6bf, w6t, b6, g6, bl6,
                                                            frozen, needed, yx, N_NODES_C);
  // yx = x1 fp32; agg6bf + frozbf dead

  // phase B: rb weight transposes (into aggregion + rbW2t) + gene convert
  {
    TArgs a;
    for (int i = 0; i < NBLK_C; ++i) {
      a.seg[i] = {rbW1 + (size_t)i * HID_C * 4 * HID_C,
                  rbW1t + (size_t)i * HID_C * 4 * HID_C, HID_C, 4 * HID_C};
      a.seg[6 + i] = {rbW2 + (size_t)i * 4 * HID_C * HID_C,
                      rbW2t + (size_t)i * 4 * HID_C * HID_C, 4 * HID_C, HID_C};
    }
    a.nseg = 12;
    multitrans_kernel<<<2048, 256, 0, stream>>>(a);
  }
  {
    CvtArgs a;
    a.seg[0] = {gene, genebf, (long long)NGENES_C * RANK_C};
    a.nseg = 1;
    multicvt_kernel<<<512, 256, 0, stream>>>(a);
  }

  // head: conv7 (round-6 unfused path)
  agg_sel_kernel<<<B_C, 256, 0, stream>>>(node_idx, ep, off, yx, agg7bf);
  {
    dim3 g(B_C / 64, GNN_C / 64);
    mgemm64_kernel<<<g, 256, 0, stream>>>(agg7bf, w7t, b7, y7b, nullptr,
                                          B_C, GNN_C, GNN_C, 0);
  }
  postconv7_kernel<<<B_C, 256, 0, stream>>>(y7b, g7, bl7, node_idx, yx, x2bf);

  // post_mp + OOV + in_ln
  {
    dim3 g(B_C / 64, GNN_C / 64);
    mgemm64_kernel<<<g, 256, 0, stream>>>(x2bf, postWt, postb, nemb, nullptr,
                                          B_C, GNN_C, GNN_C, 0);
  }
  h0ln_kernel<<<B_C, 256, 0, stream>>>(nemb, node_idx, oov, ing, inb, h0lbf);

  // proj_in -> h fp32
  {
    dim3 g(B_C / 64, HID_C / 64);
    mgemm64_kernel<<<g, 256, 0, stream>>>(h0lbf, projWt, projb, h, nullptr,
                                          B_C, HID_C, GNN_C, 0);
  }
  lnbf_kernel<<<B_C, 256, 0, stream>>>(h, rbg, rbb, tbf);

  // residual blocks: W1(gelu) -> W2 split-K -> combine+LN(next)
  for (int i = 0; i < NBLK_C; ++i) {
    {
      dim3 g(B_C / 64, (4 * HID_C) / 64);
      mgemm64_kernel<<<g, 256, 0, stream>>>(tbf, rbW1t + (size_t)i * HID_C * 4 * HID_C,
                                            rbb1 + (size_t)i * 4 * HID_C, nullptr, ubf,
                                            B_C, 4 * HID_C, HID_C, 1);
    }
    {
      dim3 g(B_C / 64, HID_C / 64, 4);
      skmgemm64_kernel<<<g, 256, 0, stream>>>(ubf, rbW2t + (size_t)i * 4 * HID_C * HID_C,
                                              part, B_C, HID_C, 4 * HID_C, HID_C);
    }
    const float* gn = (i < NBLK_C - 1) ? rbg + (size_t)(i + 1) * HID_C : outg;
    const float* bn = (i < NBLK_C - 1) ? rbb + (size_t)(i + 1) * HID_C : outb;
    combln_kernel<<<B_C, 256, 0, stream>>>(part, h, rbb2 + (size_t)i * HID_C, gn, bn, tbf);
  }

  // bilinear -> pert bf16
  {
    dim3 g(B_C / 64, (NCLS_C * RANK_C) / 64);
    mgemm64_kernel<<<g, 256, 0, stream>>>(tbf, bilWt, bilb, nullptr, pertbf,
                                          B_C, NCLS_C * RANK_C, HID_C, 0);
  }

  // logits = pert[768,512] @ gene^T -> d_out fp32
  {
    dim3 g((B_C * NCLS_C) / 128, (NGENES_C + 127) / 128);
    mgemm_kernel<<<g, 256, 0, stream>>>(pertbf, genebf, nullptr, (float*)d_out,
                                        B_C * NCLS_C, NGENES_C, RANK_C);
  }
}

// Round 11
// 572.470 us; speedup vs baseline: 1.0382x; 1.0382x over previous
//
#include <hip/hip_runtime.h>
#include <hip/hip_bf16.h>
#include <cstdint>
#include <cstddef>

#define N_NODES_C 19385
#define N_EDGES_C 1200000
#define GNN_C 256
#define HID_C 512
#define RANK_C 512
#define NCLS_C 3
#define NGENES_C 6640
#define NBLK_C 6
#define B_C 256
#define LN_EPS 1e-5f

// private-histogram geometry: K blocks (one per CU), each owns ~E/K contiguous
// edges, 1024 threads (16 waves/CU) for latency hiding. Packed dual-16b LDS
// bins; per-half chunk count <= 4688 < 65536 and per-half cross-block prefix
// <= node in-degree (<65536) -> no overflow.
#define PH_K 256
#define PH_CHUNK ((N_EDGES_C + PH_K - 1) / PH_K)  // 4688
#define PH_NW ((N_NODES_C + 1) / 2)               // 9693 packed words (38.8 KB LDS)

typedef short bf8v __attribute__((ext_vector_type(8)));
typedef float f4v __attribute__((ext_vector_type(4)));
typedef int i2v __attribute__((ext_vector_type(2)));  // packed (src*GNN, bits(w))

__device__ __forceinline__ float bfu2f(unsigned short u) {
  union { unsigned int i; float f; } c; c.i = ((unsigned)u) << 16; return c.f;
}
__device__ __forceinline__ unsigned short f2bfu(float v) {
  union { float f; unsigned u; } c; c.f = v;
  unsigned r = c.u + 0x7FFFu + ((c.u >> 16) & 1u);
  return (unsigned short)(r >> 16);
}
__device__ __forceinline__ float gelu_tanh(float v) {
  const float x3 = v * v * v;
  return 0.5f * v * (1.f + tanhf(0.7978845608028654f * (v + 0.044715f * x3)));
}

// ---------------- batched fp32 -> bf16 convert ----------------

struct CvtSeg { const float* s; unsigned short* d; long long n; };
struct CvtArgs { CvtSeg seg[2]; int nseg; };

__global__ __launch_bounds__(256) void multicvt_kernel(CvtArgs a) {
  for (int sg = 0; sg < a.nseg; ++sg) {
    const float4* s = reinterpret_cast<const float4*>(a.seg[sg].s);
    unsigned short* d = a.seg[sg].d;
    const long long n4 = a.seg[sg].n >> 2;
    for (long long i = blockIdx.x * 256 + threadIdx.x; i < n4;
         i += (long long)gridDim.x * 256) {
      float4 v = s[i];
      ushort4 o;
      o.x = f2bfu(v.x); o.y = f2bfu(v.y); o.z = f2bfu(v.z); o.w = f2bfu(v.w);
      *reinterpret_cast<ushort4*>(d + i * 4) = o;
    }
  }
}

// ---------------- batched fp32 [R,C] -> bf16 transposed [C,R] ----------------

struct TSeg { const float* s; unsigned short* d; int R, C; };
struct TArgs { TSeg seg[12]; int nseg; };

__global__ __launch_bounds__(256) void multitrans_kernel(TArgs a) {
  __shared__ float tile[32][33];
  const int tx = threadIdx.x & 31;
  const int ty = threadIdx.x >> 5;  // 8 rows/pass
  for (int sg = 0; sg < a.nseg; ++sg) {
    const int R = a.seg[sg].R, C = a.seg[sg].C;
    const int tC = C >> 5;
    const int nt = (R >> 5) * tC;
    const float* src = a.seg[sg].s;
    unsigned short* dst = a.seg[sg].d;
    for (int tid = blockIdx.x; tid < nt; tid += gridDim.x) {
      const int tr = tid / tC, tc = tid - tr * tC;
      const int r0 = tr * 32, c0 = tc * 32;
      __syncthreads();
#pragma unroll
      for (int j = 0; j < 32; j += 8)
        tile[ty + j][tx] = src[(size_t)(r0 + ty + j) * C + c0 + tx];
      __syncthreads();
#pragma unroll
      for (int j = 0; j < 32; j += 8)
        dst[(size_t)(c0 + ty + j) * R + r0 + tx] = f2bfu(tile[tx][ty + j]);
    }
  }
}

// ---------------- frontier marking (fused zero+set: no memsets, no races) ----

__global__ __launch_bounds__(256) void initmark_kernel(const int* __restrict__ node_idx,
                                                       int* __restrict__ selbm,
                                                       int* __restrict__ needed) {
  __shared__ int sel[B_C];
  sel[threadIdx.x] = max(node_idx[threadIdx.x], 0);  // 256 threads == B_C
  __syncthreads();
  for (int i = blockIdx.x * 256 + threadIdx.x; i < N_NODES_C;
       i += gridDim.x * 256) {
    int m = 0;
#pragma unroll 16
    for (int j = 0; j < B_C; ++j) m |= (sel[j] == i);
    selbm[i] = m;
    needed[i] = m;
  }
}

// per-block private LDS histogram (packed 2x16b) + frontier source marking.
// ZERO global atomics: each block flushes its bins with plain coalesced stores.
__global__ __launch_bounds__(1024) void privhist_kernel(const int* __restrict__ src,
                                                        const int* __restrict__ dst,
                                                        const int* __restrict__ selbm,
                                                        int* __restrict__ needed,
                                                        unsigned int* __restrict__ cntp) {
  __shared__ unsigned int bins[PH_NW];
  const int t = threadIdx.x;
  for (int w = t; w < PH_NW; w += 1024) bins[w] = 0u;
  __syncthreads();
  const int base = blockIdx.x * PH_CHUNK;
  const int end = min(base + PH_CHUNK, N_EDGES_C);
#pragma unroll 2
  for (int i = base + t; i < end; i += 1024) {
    const int d = dst[i];
    atomicAdd(&bins[d >> 1], 1u << ((d & 1) * 16));
    if (selbm[d]) needed[src[i]] = 1;
  }
  __syncthreads();
  unsigned int* out = cntp + (size_t)blockIdx.x * PH_NW;
  for (int w = t; w < PH_NW; w += 1024) out[w] = bins[w];
}

// sum the PH_K packed private histograms -> per-node degree (int), and
// REPLACE cntp[k][w] in place with the packed EXCLUSIVE cross-block prefix.
__global__ __launch_bounds__(256) void redhist_kernel(unsigned int* __restrict__ cntp,
                                                      int* __restrict__ cnt) {
  const int w = blockIdx.x * 256 + threadIdx.x;
  if (w >= PH_NW) return;
  unsigned int lo = 0, hi = 0;
#pragma unroll 4
  for (int k = 0; k < PH_K; ++k) {
    const size_t idx = (size_t)k * PH_NW + w;
    const unsigned int u = cntp[idx];
    cntp[idx] = lo | (hi << 16);
    lo += u & 0xFFFFu;
    hi += u >> 16;
  }
  cnt[2 * w] = (int)lo;
  if (2 * w + 1 < N_NODES_C) cnt[2 * w + 1] = (int)hi;
}

__global__ __launch_bounds__(1024) void scan_kernel(const int* __restrict__ cnt,
                                                    int* __restrict__ off, int n) {
  __shared__ int sums[1024];
  const int t = threadIdx.x;
  const int CH = (n + 1023) >> 10;
  const int base = t * CH;
  int s = 0;
  for (int i = 0; i < CH; ++i) {
    int idx = base + i;
    if (idx < n) s += cnt[idx];
  }
  sums[t] = s;
  __syncthreads();
  for (int d = 1; d < 1024; d <<= 1) {
    int v = (t >= d) ? sums[t - d] : 0;
    __syncthreads();
    sums[t] += v;
    __syncthreads();
  }
  int run = (t == 0) ? 0 : sums[t - 1];
  for (int i = 0; i < CH; ++i) {
    int idx = base + i;
    if (idx < n) { off[idx] = run; run += cnt[idx]; }
  }
  if (t == 0) off[n] = sums[1023];
}

// deterministic-slot scatter, ZERO global atomics (prefix-seeded LDS ranks).
__global__ __launch_bounds__(1024) void fill_kernel(const int* __restrict__ src,
                                                    const int* __restrict__ dst,
                                                    const float* __restrict__ ew,
                                                    const int* __restrict__ off,
                                                    const unsigned int* __restrict__ cntp,
                                                    const int* __restrict__ needed,
                                                    i2v* __restrict__ ep) {
  __shared__ unsigned int bins[PH_NW];
  const int t = threadIdx.x;
  const unsigned int* myp = cntp + (size_t)blockIdx.x * PH_NW;
  for (int w = t; w < PH_NW; w += 1024) bins[w] = myp[w];
  __syncthreads();
  const int base = blockIdx.x * PH_CHUNK;
  const int end = min(base + PH_CHUNK, N_EDGES_C);
#pragma unroll 2
  for (int i = base + t; i < end; i += 1024) {
    const int d = dst[i];
    if (!needed[d]) continue;
    const int sh = (d & 1) * 16;
    const unsigned int old = atomicAdd(&bins[d >> 1], 1u << sh);
    const int rank = (int)((old >> sh) & 0xFFFFu);
    i2v e;
    e[0] = src[i] * GNN_C;
    e[1] = __float_as_int(ew[i]);
    ep[off[d] + rank] = e;
  }
}

// ---------------- edge aggregation ----------------

__global__ __launch_bounds__(256) void agg_full_kernel(const i2v* __restrict__ ep,
                                                       const int* __restrict__ off,
                                                       const int* __restrict__ needed,
                                                       const unsigned short* __restrict__ x,
                                                       unsigned short* __restrict__ aggbf) {
  const int n = blockIdx.x;
  if (!needed[n]) return;  // uniform: whole block exits together
  __shared__ f4v red[4][64];
  const int t = threadIdx.x;
  const int w = __builtin_amdgcn_readfirstlane(t >> 6);
  const int lane = t & 63;
  const int s0 = off[n];
  const int c = off[n + 1] - s0;
  const int q0 = s0 + ((c * w) >> 2);
  const int q1 = s0 + ((c * (w + 1)) >> 2);
  float a0 = 0.f, a1 = 0.f, a2 = 0.f, a3 = 0.f;
  const unsigned short* xl = x + 4 * lane;
#pragma unroll 4
  for (int p = q0; p < q1; ++p) {
    const i2v e = ep[p];  // wave-uniform -> s_load_dwordx2
    const int s = e[0];
    const float wg = __int_as_float(e[1]);
    const ushort4 v = *reinterpret_cast<const ushort4*>(xl + s);
    a0 = fmaf(bfu2f(v.x), wg, a0);
    a1 = fmaf(bfu2f(v.y), wg, a1);
    a2 = fmaf(bfu2f(v.z), wg, a2);
    a3 = fmaf(bfu2f(v.w), wg, a3);
  }
  f4v av; av[0] = a0; av[1] = a1; av[2] = a2; av[3] = a3;
  red[w][lane] = av;
  __syncthreads();
  const float* rf = reinterpret_cast<const float*>(red);
  const float sum = rf[t] + rf[256 + t] + rf[512 + t] + rf[768 + t];
  aggbf[(size_t)n * GNN_C + t] = f2bfu(sum);
}

__global__ __launch_bounds__(256) void agg_sel_kernel(const int* __restrict__ node_idx,
                                                      const i2v* __restrict__ ep,
                                                      const int* __restrict__ off,
                                                      const float* __restrict__ x,
                                                      unsigned short* __restrict__ aggbf) {
  __shared__ f4v red[4][64];
  const int b = blockIdx.x;
  const int t = threadIdx.x;
  const int n = max(node_idx[b], 0);
  const int w = __builtin_amdgcn_readfirstlane(t >> 6);
  const int lane = t & 63;
  const int s0 = off[n];
  const int c = off[n + 1] - s0;
  const int q0 = s0 + ((c * w) >> 2);
  const int q1 = s0 + ((c * (w + 1)) >> 2);
  float a0 = 0.f, a1 = 0.f, a2 = 0.f, a3 = 0.f;
  const float* xl = x + 4 * lane;
#pragma unroll 2
  for (int p = q0; p < q1; ++p) {
    const i2v e = ep[p];
    const int s = e[0];
    const float wg = __int_as_float(e[1]);
    const f4v v = *reinterpret_cast<const f4v*>(xl + s);
    a0 = fmaf(v[0], wg, a0);
    a1 = fmaf(v[1], wg, a1);
    a2 = fmaf(v[2], wg, a2);
    a3 = fmaf(v[3], wg, a3);
  }
  f4v av; av[0] = a0; av[1] = a1; av[2] = a2; av[3] = a3;
  red[w][lane] = av;
  __syncthreads();
  const float* rf = reinterpret_cast<const float*>(red);
  const float sum = rf[t] + rf[256 + t] + rf[512 + t] + rf[768 + t];
  aggbf[(size_t)b * GNN_C + t] = f2bfu(sum);
}

// ---------------- MFMA bf16 GEMM 128x128, transB only ----------------

#define MBK 32
#define MLDW 40

__global__ __launch_bounds__(256) void mgemm_kernel(const unsigned short* __restrict__ A,
                                                    const unsigned short* __restrict__ Bt,
                                                    const float* __restrict__ bias,
                                                    float* __restrict__ C,
                                                    int M, int N, int K) {
  __shared__ unsigned short As[128][MLDW];
  __shared__ unsigned short Bs[128][MLDW];
  const int t = threadIdx.x;
  const int lane = t & 63;
  const int wave = t >> 6;
  const int r0 = blockIdx.x * 128;
  const int c0 = blockIdx.y * 128;
  const int wm = (wave >> 1) * 64;
  const int wn = (wave & 1) * 64;
  const int lm = lane & 15;
  const int lq = lane >> 4;

  f4v acc[4][4];
  for (int i = 0; i < 4; ++i)
    for (int j = 0; j < 4; ++j)
      for (int r = 0; r < 4; ++r) acc[i][j][r] = 0.f;

  const int row = t >> 1;
  const int kof = (t & 1) * 16;
  for (int k0 = 0; k0 < K; k0 += MBK) {
    {
      const int gr = r0 + row;
      uint4 u0 = make_uint4(0, 0, 0, 0), u1 = u0;
      if (gr < M) {
        const uint4* p = reinterpret_cast<const uint4*>(A + (size_t)gr * K + k0 + kof);
        u0 = p[0]; u1 = p[1];
      }
      *reinterpret_cast<uint4*>(&As[row][kof]) = u0;
      *reinterpret_cast<uint4*>(&As[row][kof + 8]) = u1;
    }
    {
      const int gn = c0 + row;
      uint4 u0 = make_uint4(0, 0, 0, 0), u1 = u0;
      if (gn < N) {
        const uint4* p = reinterpret_cast<const uint4*>(Bt + (size_t)gn * K + k0 + kof);
        u0 = p[0]; u1 = p[1];
      }
      *reinterpret_cast<uint4*>(&Bs[row][kof]) = u0;
      *reinterpret_cast<uint4*>(&Bs[row][kof + 8]) = u1;
    }
    __syncthreads();

    bf8v a[4], b[4];
#pragma unroll
    for (int i = 0; i < 4; ++i)
      a[i] = *reinterpret_cast<const bf8v*>(&As[wm + i * 16 + lm][lq * 8]);
#pragma unroll
    for (int j = 0; j < 4; ++j)
      b[j] = *reinterpret_cast<const bf8v*>(&Bs[wn + j * 16 + lm][lq * 8]);
#pragma unroll
    for (int i = 0; i < 4; ++i)
#pragma unroll
      for (int j = 0; j < 4; ++j)
        acc[i][j] = __builtin_amdgcn_mfma_f32_16x16x32_bf16(a[i], b[j], acc[i][j], 0, 0, 0);
    __syncthreads();
  }

  for (int ti = 0; ti < 4; ++ti) {
    for (int tj = 0; tj < 4; ++tj) {
      const int col = c0 + wn + tj * 16 + lm;
      if (col >= N) continue;
      const float bv = bias ? bias[col] : 0.f;
      for (int r = 0; r < 4; ++r) {
        const int row2 = r0 + wm + ti * 16 + lq * 4 + r;
        if (row2 < M) C[(size_t)row2 * N + col] = acc[ti][tj][r] + bv;
      }
    }
  }
}

// ---------------- MFMA bf16 GEMM 64x64, transB, fused epilogue ----------------

__global__ __launch_bounds__(256) void mgemm64_kernel(const unsigned short* __restrict__ A,
                                                      const unsigned short* __restrict__ Bt,
                                                      const float* __restrict__ bias,
                                                      float* outF, unsigned short* outB,
                                                      int M, int N, int K, int doGelu) {
  __shared__ unsigned short As[64][MLDW];
  __shared__ unsigned short Bs[64][MLDW];
  const int t = threadIdx.x;
  const int lane = t & 63;
  const int wave = t >> 6;
  const int r0 = blockIdx.x * 64;
  const int c0 = blockIdx.y * 64;
  const int wm = (wave >> 1) * 32;
  const int wn = (wave & 1) * 32;
  const int lm = lane & 15;
  const int lq = lane >> 4;

  f4v acc[2][2];
  for (int i = 0; i < 2; ++i)
    for (int j = 0; j < 2; ++j)
      for (int r = 0; r < 4; ++r) acc[i][j][r] = 0.f;

  const int row = t >> 2;
  const int kof = (t & 3) * 8;
  for (int k0 = 0; k0 < K; k0 += MBK) {
    *reinterpret_cast<uint4*>(&As[row][kof]) =
        *reinterpret_cast<const uint4*>(A + (size_t)(r0 + row) * K + k0 + kof);
    *reinterpret_cast<uint4*>(&Bs[row][kof]) =
        *reinterpret_cast<const uint4*>(Bt + (size_t)(c0 + row) * K + k0 + kof);
    __syncthreads();
    bf8v a[2], b[2];
#pragma unroll
    for (int i = 0; i < 2; ++i)
      a[i] = *reinterpret_cast<const bf8v*>(&As[wm + i * 16 + lm][lq * 8]);
#pragma unroll
    for (int j = 0; j < 2; ++j)
      b[j] = *reinterpret_cast<const bf8v*>(&Bs[wn + j * 16 + lm][lq * 8]);
#pragma unroll
    for (int i = 0; i < 2; ++i)
#pragma unroll
      for (int j = 0; j < 2; ++j)
        acc[i][j] = __builtin_amdgcn_mfma_f32_16x16x32_bf16(a[i], b[j], acc[i][j], 0, 0, 0);
    __syncthreads();
  }

  for (int ti = 0; ti < 2; ++ti) {
    for (int tj = 0; tj < 2; ++tj) {
      const int col = c0 + wn + tj * 16 + lm;
      const float bv = bias ? bias[col] : 0.f;
      for (int r = 0; r < 4; ++r) {
        const int row2 = r0 + wm + ti * 16 + lq * 4 + r;
        float v = acc[ti][tj][r] + bv;
        if (doGelu) v = gelu_tanh(v);
        if (outF) outF[(size_t)row2 * N + col] = v;
        else outB[(size_t)row2 * N + col] = f2bfu(v);
      }
    }
  }
}

// split-K variant: grid.z slices write raw fp32 partials part[z][M][N]
__global__ __launch_bounds__(256) void skmgemm64_kernel(const unsigned short* __restrict__ A,
                                                        const unsigned short* __restrict__ Bt,
                                                        float* __restrict__ part,
                                                        int M, int N, int K, int kc) {
  __shared__ unsigned short As[64][MLDW];
  __shared__ unsigned short Bs[64][MLDW];
  const int t = threadIdx.x;
  const int lane = t & 63;
  const int wave = t >> 6;
  const int r0 = blockIdx.x * 64;
  const int c0 = blockIdx.y * 64;
  const int kBeg = blockIdx.z * kc;
  const int kEnd = kBeg + kc;
  const int wm = (wave >> 1) * 32;
  const int wn = (wave & 1) * 32;
  const int lm = lane & 15;
  const int lq = lane >> 4;

  f4v acc[2][2];
  for (int i = 0; i < 2; ++i)
    for (int j = 0; j < 2; ++j)
      for (int r = 0; r < 4; ++r) acc[i][j][r] = 0.f;

  const int row = t >> 2;
  const int kof = (t & 3) * 8;
  for (int k0 = kBeg; k0 < kEnd; k0 += MBK) {
    *reinterpret_cast<uint4*>(&As[row][kof]) =
        *reinterpret_cast<const uint4*>(A + (size_t)(r0 + row) * K + k0 + kof);
    *reinterpret_cast<uint4*>(&Bs[row][kof]) =
        *reinterpret_cast<const uint4*>(Bt + (size_t)(c0 + row) * K + k0 + kof);
    __syncthreads();
    bf8v a[2], b[2];
#pragma unroll
    for (int i = 0; i < 2; ++i)
      a[i] = *reinterpret_cast<const bf8v*>(&As[wm + i * 16 + lm][lq * 8]);
#pragma unroll
    for (int j = 0; j < 2; ++j)
      b[j] = *reinterpret_cast<const bf8v*>(&Bs[wn + j * 16 + lm][lq * 8]);
#pragma unroll
    for (int i = 0; i < 2; ++i)
#pragma unroll
      for (int j = 0; j < 2; ++j)
        acc[i][j] = __builtin_amdgcn_mfma_f32_16x16x32_bf16(a[i], b[j], acc[i][j], 0, 0, 0);
    __syncthreads();
  }

  float* out = part + (size_t)blockIdx.z * M * N;
  for (int ti = 0; ti < 2; ++ti)
    for (int tj = 0; tj < 2; ++tj) {
      const int col = c0 + wn + tj * 16 + lm;
      for (int r = 0; r < 4; ++r) {
        const int row2 = r0 + wm + ti * 16 + lq * 4 + r;
        out[(size_t)row2 * N + col] = acc[ti][tj][r];
      }
    }
}

// ---------------- fused conv6 GEMM + LayerNorm (v2: 32-row blocks) ----------------
// 32-row x 256-col blocks, 8 waves (512 thr); wave w owns cols [w*32,(w+1)*32).
// 606 blocks (~2.4/CU) so staging/barrier stalls overlap across blocks.
// B-staging: one uint4 (8 shorts) per id at row id>>2, kof (id&3)*8 -> full
// 256x32 coverage (1024 ids x 8 shorts = 8192), 16B-aligned (row stride 80B).
// conv6: yx[row] = frozen[row] + relu(LN(agg@W6 + b6)) for needed rows only.
__global__ __launch_bounds__(512) void gemmln6_kernel(const unsigned short* __restrict__ A,
                                                      const unsigned short* __restrict__ Bt,
                                                      const float* __restrict__ bias,
                                                      const float* __restrict__ g,
                                                      const float* __restrict__ b,
                                                      const float* __restrict__ frozen,
                                                      const int* __restrict__ needed,
                                                      float* __restrict__ yx, int M) {
  __shared__ unsigned short As[32][MLDW];
  __shared__ unsigned short Bs[256][MLDW];
  __shared__ float rs[32][8];
  const int t = threadIdx.x;
  const int lane = t & 63;
  const int wave = t >> 6;  // 0..7
  const int r0 = blockIdx.x * 32;
  const int lm = lane & 15, lq = lane >> 4;

  f4v acc[2][2];
#pragma unroll
  for (int i = 0; i < 2; ++i)
#pragma unroll
    for (int j = 0; j < 2; ++j)
#pragma unroll
      for (int r = 0; r < 4; ++r) acc[i][j][r] = 0.f;

  const int arow = t >> 3, akof = (t & 7) * 4;  // t<256: 32 rows x 32k ushort4
  for (int k0 = 0; k0 < GNN_C; k0 += MBK) {
    if (t < 256) {
      ushort4 u = make_ushort4(0, 0, 0, 0);
      const int gr = r0 + arow;
      if (gr < M) u = *reinterpret_cast<const ushort4*>(A + (size_t)gr * GNN_C + k0 + akof);
      *reinterpret_cast<ushort4*>(&As[arow][akof]) = u;
    }
#pragma unroll
    for (int j = 0; j < 2; ++j) {
      const int id = t + 512 * j;
      const int brow = id >> 2, bkof = (id & 3) * 8;
      *reinterpret_cast<uint4*>(&Bs[brow][bkof]) =
          *reinterpret_cast<const uint4*>(Bt + (size_t)brow * GNN_C + k0 + bkof);
    }
    __syncthreads();
    bf8v a[2], bf[2];
#pragma unroll
    for (int ti = 0; ti < 2; ++ti)
      a[ti] = *reinterpret_cast<const bf8v*>(&As[ti * 16 + lm][lq * 8]);
#pragma unroll
    for (int tj = 0; tj < 2; ++tj)
      bf[tj] = *reinterpret_cast<const bf8v*>(&Bs[wave * 32 + tj * 16 + lm][lq * 8]);
#pragma unroll
    for (int ti = 0; ti < 2; ++ti)
#pragma unroll
      for (int tj = 0; tj < 2; ++tj)
        acc[ti][tj] = __builtin_amdgcn_mfma_f32_16x16x32_bf16(a[ti], bf[tj], acc[ti][tj], 0, 0, 0);
    __syncthreads();
  }

  // + bias (pre-LN, matches reference y6 = agg@W + b)
  const int c0 = wave * 32 + lm, c1 = c0 + 16;
  const float b0 = bias[c0], b1 = bias[c1];
#pragma unroll
  for (int ti = 0; ti < 2; ++ti)
#pragma unroll
    for (int r = 0; r < 4; ++r) { acc[ti][0][r] += b0; acc[ti][1][r] += b1; }

  // mean
  float m[2][4];
#pragma unroll
  for (int ti = 0; ti < 2; ++ti)
#pragma unroll
    for (int r = 0; r < 4; ++r) {
      float s = acc[ti][0][r] + acc[ti][1][r];
      for (int o = 1; o < 16; o <<= 1) s += __shfl_xor(s, o, 64);
      if (lm == 0) rs[ti * 16 + lq * 4 + r][wave] = s;
    }
  __syncthreads();
#pragma unroll
  for (int ti = 0; ti < 2; ++ti)
#pragma unroll
    for (int r = 0; r < 4; ++r) {
      const int row = ti * 16 + lq * 4 + r;
      float s = 0.f;
#pragma unroll
      for (int w2 = 0; w2 < 8; ++w2) s += rs[row][w2];
      m[ti][r] = s * (1.f / GNN_C);
    }
  __syncthreads();
  // variance
  float iv[2][4];
#pragma unroll
  for (int ti = 0; ti < 2; ++ti)
#pragma unroll
    for (int r = 0; r < 4; ++r) {
      const float d0 = acc[ti][0][r] - m[ti][r];
      const float d1 = acc[ti][1][r] - m[ti][r];
      float s = d0 * d0 + d1 * d1;
      for (int o = 1; o < 16; o <<= 1) s += __shfl_xor(s, o, 64);
      if (lm == 0) rs[ti * 16 + lq * 4 + r][wave] = s;
    }
  __syncthreads();
#pragma unroll
  for (int ti = 0; ti < 2; ++ti)
#pragma unroll
    for (int r = 0; r < 4; ++r) {
      const int row = ti * 16 + lq * 4 + r;
      float s = 0.f;
#pragma unroll
      for (int w2 = 0; w2 < 8; ++w2) s += rs[row][w2];
      iv[ti][r] = rsqrtf(s * (1.f / GNN_C) + LN_EPS);
    }

  const float g0 = g[c0], g1 = g[c1], bb0 = b[c0], bb1 = b[c1];
#pragma unroll
  for (int ti = 0; ti < 2; ++ti)
#pragma unroll
    for (int r = 0; r < 4; ++r) {
      const int grow = r0 + ti * 16 + lq * 4 + r;
      if (grow < M && needed[grow]) {
        const size_t base = (size_t)grow * GNN_C;
        const float x0 = fmaxf((acc[ti][0][r] - m[ti][r]) * iv[ti][r] * g0 + bb0, 0.f);
        const float x1 = fmaxf((acc[ti][1][r] - m[ti][r]) * iv[ti][r] * g1 + bb1, 0.f);
        yx[base + c0] = frozen[base + c0] + x0;
        yx[base + c1] = frozen[base + c1] + x1;
      }
    }
}

// ---------------- LN family (head path) ----------------

__global__ __launch_bounds__(256) void postconv7_kernel(const float* __restrict__ y,
                                                        const float* __restrict__ g,
                                                        const float* __restrict__ b,
                                                        const int* __restrict__ idx,
                                                        const float* __restrict__ x1f,
                                                        unsigned short* __restrict__ out) {
  __shared__ float sb[4];
  const int bi = blockIdx.x, t = threadIdx.x;
  const int n = max(idx[bi], 0);
  const float v = y[(size_t)bi * GNN_C + t];
  float s = v;
  for (int o = 32; o; o >>= 1) s += __shfl_down(s, o, 64);
  if ((t & 63) == 0) sb[t >> 6] = s;
  __syncthreads();
  const float m = (sb[0] + sb[1] + sb[2] + sb[3]) * (1.f / GNN_C);
  __syncthreads();
  const float d = v - m;
  s = d * d;
  for (int o = 32; o; o >>= 1) s += __shfl_down(s, o, 64);
  if ((t & 63) == 0) sb[t >> 6] = s;
  __syncthreads();
  const float rs = rsqrtf((sb[0] + sb[1] + sb[2] + sb[3]) * (1.f / GNN_C) + LN_EPS);
  const float xn = d * rs * g[t] + b[t];
  out[(size_t)bi * GNN_C + t] = f2bfu(x1f[(size_t)n * GNN_C + t] + fmaxf(xn, 0.f));
}

__global__ __launch_bounds__(256) void h0ln_kernel(const float* __restrict__ ne,
                                                   const int* __restrict__ idx,
                                                   const float* __restrict__ oov,
                                                   const float* __restrict__ g,
                                                   const float* __restrict__ b,
                                                   unsigned short* __restrict__ out) {
  __shared__ float sb[4];
  const int bi = blockIdx.x, t = threadIdx.x;
  const float v = (idx[bi] >= 0) ? ne[(size_t)bi * GNN_C + t] : oov[t];
  float s = v;
  for (int o = 32; o; o >>= 1) s += __shfl_down(s, o, 64);
  if ((t & 63) == 0) sb[t >> 6] = s;
  __syncthreads();
  const float m = (sb[0] + sb[1] + sb[2] + sb[3]) * (1.f / GNN_C);
  __syncthreads();
  const float d = v - m;
  s = d * d;
  for (int o = 32; o; o >>= 1) s += __shfl_down(s, o, 64);
  if ((t & 63) == 0) sb[t >> 6] = s;
  __syncthreads();
  const float rs = rsqrtf((sb[0] + sb[1] + sb[2] + sb[3]) * (1.f / GNN_C) + LN_EPS);
  out[(size_t)bi * GNN_C + t] = f2bfu(d * rs * g[t] + b[t]);
}

// plain LN over 512-rows of h -> bf16
__global__ __launch_bounds__(256) void lnbf_kernel(const float* __restrict__ in,
                                                   const float* __restrict__ g,
                                                   const float* __restrict__ b,
                                                   unsigned short* __restrict__ out) {
  __shared__ float sb[4];
  const int r = blockIdx.x, t = threadIdx.x;
  const float v0 = in[(size_t)r * HID_C + t];
  const float v1 = in[(size_t)r * HID_C + t + 256];
  float s = v0 + v1;
  for (int o = 32; o; o >>= 1) s += __shfl_down(s, o, 64);
  if ((t & 63) == 0) sb[t >> 6] = s;
  __syncthreads();
  const float m = (sb[0] + sb[1] + sb[2] + sb[3]) * (1.f / HID_C);
  __syncthreads();
  const float d0 = v0 - m, d1 = v1 - m;
  s = d0 * d0 + d1 * d1;
  for (int o = 32; o; o >>= 1) s += __shfl_down(s, o, 64);
  if ((t & 63) == 0) sb[t >> 6] = s;
  __syncthreads();
  const float rs = rsqrtf((sb[0] + sb[1] + sb[2] + sb[3]) * (1.f / HID_C) + LN_EPS);
  out[(size_t)r * HID_C + t] = f2bfu(d0 * rs * g[t] + b[t]);
  out[(size_t)r * HID_C + t + 256] = f2bfu(d1 * rs * g[t + 256] + b[t + 256]);
}

// combine split-K partials + bias + residual into h, then LN (next gamma/beta) -> bf16
__global__ __launch_bounds__(256) void combln_kernel(const float* __restrict__ part,
                                                     float* __restrict__ h,
                                                     const float* __restrict__ b2,
                                                     const float* __restrict__ g,
                                                     const float* __restrict__ b,
                                                     unsigned short* __restrict__ out) {
  __shared__ float sb[4];
  const int r = blockIdx.x, t = threadIdx.x;
  const int MN = B_C * HID_C;
  const size_t o0 = (size_t)r * HID_C + t;
  const size_t o1 = o0 + 256;
  float v0 = h[o0] + b2[t] + part[o0] + part[MN + o0] + part[2 * MN + o0] + part[3 * MN + o0];
  float v1 = h[o1] + b2[t + 256] + part[o1] + part[MN + o1] + part[2 * MN + o1] + part[3 * MN + o1];
  h[o0] = v0;
  h[o1] = v1;
  float s = v0 + v1;
  for (int o = 32; o; o >>= 1) s += __shfl_down(s, o, 64);
  if ((t & 63) == 0) sb[t >> 6] = s;
  __syncthreads();
  const float m = (sb[0] + sb[1] + sb[2] + sb[3]) * (1.f / HID_C);
  __syncthreads();
  const float d0 = v0 - m, d1 = v1 - m;
  s = d0 * d0 + d1 * d1;
  for (int o = 32; o; o >>= 1) s += __shfl_down(s, o, 64);
  if ((t & 63) == 0) sb[t >> 6] = s;
  __syncthreads();
  const float rsq = rsqrtf((sb[0] + sb[1] + sb[2] + sb[3]) * (1.f / HID_C) + LN_EPS);
  out[o0] = f2bfu(d0 * rsq * g[t] + b[t]);
  out[o1] = f2bfu(d1 * rsq * g[t + 256] + b[t + 256]);
}

// ---------------- host ----------------

extern "C" void kernel_launch(void* const* d_in, const int* in_sizes, int n_in,
                              void* d_out, int out_size, void* d_ws, size_t ws_size,
                              hipStream_t stream) {
  const int* node_idx = (const int*)d_in[0];
  const int* e_src = (const int*)d_in[1];
  const int* e_dst = e_src + N_EDGES_C;
  const float* ew = (const float*)d_in[2];
  const float* frozen = (const float*)d_in[3];
  const float* W6 = (const float*)d_in[4];
  const float* b6 = (const float*)d_in[5];
  const float* g6 = (const float*)d_in[6];
  const float* bl6 = (const float*)d_in[7];
  const float* W7 = (const float*)d_in[8];
  const float* b7 = (const float*)d_in[9];
  const float* g7 = (const float*)d_in[10];
  const float* bl7 = (const float*)d_in[11];
  const float* postW = (const float*)d_in[12];
  const float* postb = (const float*)d_in[13];
  const float* oov = (const float*)d_in[14];
  const float* ing = (const float*)d_in[15];
  const float* inb = (const float*)d_in[16];
  const float* projW = (const float*)d_in[17];
  const float* projb = (const float*)d_in[18];
  const float* rbg = (const float*)d_in[19];
  const float* rbb = (const float*)d_in[20];
  const float* rbW1 = (const float*)d_in[21];
  const float* rbb1 = (const float*)d_in[22];
  const float* rbW2 = (const float*)d_in[23];
  const float* rbb2 = (const float*)d_in[24];
  const float* outg = (const float*)d_in[25];
  const float* outb = (const float*)d_in[26];
  const float* bilW = (const float*)d_in[27];
  const float* bilb = (const float*)d_in[28];
  const float* gene = (const float*)d_in[29];
  (void)in_sizes; (void)n_in; (void)out_size; (void)ws_size;

  char* ws = (char*)d_ws;
  size_t o = 0;
  auto alloc = [&](size_t bytes) -> char* {
    char* p = ws + o;
    o += (bytes + 255) & ~(size_t)255;
    return p;
  };
  int* cnt = (int*)alloc((size_t)N_NODES_C * 4);
  int* off = (int*)alloc((size_t)(N_NODES_C + 1) * 4);
  int* needed = (int*)alloc((size_t)N_NODES_C * 4);
  int* selbm = (int*)alloc((size_t)N_NODES_C * 4);
  unsigned int* cntp = (unsigned int*)alloc((size_t)PH_K * PH_NW * 4);
  i2v* ep = (i2v*)alloc((size_t)N_EDGES_C * 8);
  unsigned short* frozbf = (unsigned short*)alloc((size_t)N_NODES_C * GNN_C * 2);
  // aggregion: agg6bf (9.93 MB, dead after conv6 GEMM) then rbW1t (12.58 MB, phase B)
  char* aggregion = alloc((size_t)NBLK_C * HID_C * 4 * HID_C * 2);
  unsigned short* w6t = (unsigned short*)alloc((size_t)GNN_C * GNN_C * 2);
  unsigned short* w7t = (unsigned short*)alloc((size_t)GNN_C * GNN_C * 2);
  unsigned short* postWt = (unsigned short*)alloc((size_t)GNN_C * GNN_C * 2);
  unsigned short* projWt = (unsigned short*)alloc((size_t)HID_C * GNN_C * 2);
  unsigned short* bilWt = (unsigned short*)alloc((size_t)NCLS_C * RANK_C * HID_C * 2);
  float* yx = (float*)alloc((size_t)N_NODES_C * GNN_C * 4);  // x1 fp32 (gated write)
  unsigned short* rbW2t = (unsigned short*)alloc((size_t)NBLK_C * 4 * HID_C * HID_C * 2);
  float* part = (float*)alloc((size_t)4 * B_C * HID_C * 4);
  unsigned short* agg7bf = (unsigned short*)alloc((size_t)B_C * GNN_C * 2);
  float* y7b = (float*)alloc((size_t)B_C * GNN_C * 4);
  unsigned short* x2bf = (unsigned short*)alloc((size_t)B_C * GNN_C * 2);
  float* nemb = (float*)alloc((size_t)B_C * GNN_C * 4);
  unsigned short* h0lbf = (unsigned short*)alloc((size_t)B_C * GNN_C * 2);
  float* h = (float*)alloc((size_t)B_C * HID_C * 4);
  unsigned short* tbf = (unsigned short*)alloc((size_t)B_C * HID_C * 2);
  unsigned short* ubf = (unsigned short*)alloc((size_t)B_C * 4 * HID_C * 2);
  unsigned short* pertbf = (unsigned short*)alloc((size_t)B_C * NCLS_C * RANK_C * 2);

  unsigned short* agg6bf = (unsigned short*)aggregion;
  unsigned short* rbW1t = (unsigned short*)aggregion;
  unsigned short* genebf = frozbf;  // frozbf dead after agg_full

  // frontier marking (fused zero+set) + privatized histogram + prefix
  // write-back, then deterministic-slot fill (zero global atomics)
  initmark_kernel<<<80, 256, 0, stream>>>(node_idx, selbm, needed);
  privhist_kernel<<<PH_K, 1024, 0, stream>>>(e_src, e_dst, selbm, needed, cntp);
  redhist_kernel<<<(PH_NW + 255) / 256, 256, 0, stream>>>(cntp, cnt);
  scan_kernel<<<1, 1024, 0, stream>>>(cnt, off, N_NODES_C);
  fill_kernel<<<PH_K, 1024, 0, stream>>>(e_src, e_dst, ew, off, cntp, needed, ep);

  // phase A: frozen convert + small weight transposes
  {
    CvtArgs a;
    a.seg[0] = {frozen, frozbf, (long long)N_NODES_C * GNN_C};
    a.nseg = 1;
    multicvt_kernel<<<512, 256, 0, stream>>>(a);
  }
  {
    TArgs a;
    a.seg[0] = {W6, w6t, GNN_C, GNN_C};
    a.seg[1] = {W7, w7t, GNN_C, GNN_C};
    a.seg[2] = {postW, postWt, GNN_C, GNN_C};
    a.seg[3] = {projW, projWt, GNN_C, HID_C};
    a.seg[4] = {bilW, bilWt, HID_C, NCLS_C * RANK_C};
    a.nseg = 5;
    multitrans_kernel<<<512, 256, 0, stream>>>(a);
  }

  // conv6 trunk: aggregate then fused GEMM + LN + ReLU + residual (gated, 32-row blocks)
  agg_full_kernel<<<N_NODES_C, 256, 0, stream>>>(ep, off, needed, frozbf, agg6bf);
  gemmln6_kernel<<<(N_NODES_C + 31) / 32, 512, 0, stream>>>(agg6bf, w6t, b6, g6, bl6,
                                                            frozen, needed, yx, N_NODES_C);
  // yx = x1 fp32; agg6bf + frozbf dead

  // phase B: rb weight transposes (into aggregion + rbW2t) + gene convert
  {
    TArgs a;
    for (int i = 0; i < NBLK_C; ++i) {
      a.seg[i] = {rbW1 + (size_t)i * HID_C * 4 * HID_C,
                  rbW1t + (size_t)i * HID_C * 4 * HID_C, HID_C, 4 * HID_C};
      a.seg[6 + i] = {rbW2 + (size_t)i * 4 * HID_C * HID_C,
                      rbW2t + (size_t)i * 4 * HID_C * HID_C, 4 * HID_C, HID_C};
    }
    a.nseg = 12;
    multitrans_kernel<<<2048, 256, 0, stream>>>(a);
  }
  {
    CvtArgs a;
    a.seg[0] = {gene, genebf, (long long)NGENES_C * RANK_C};
    a.nseg = 1;
    multicvt_kernel<<<512, 256, 0, stream>>>(a);
  }

  // head: conv7 (unfused path)
  agg_sel_kernel<<<B_C, 256, 0, stream>>>(node_idx, ep, off, yx, agg7bf);
  {
    dim3 g(B_C / 64, GNN_C / 64);
    mgemm64_kernel<<<g, 256, 0, stream>>>(agg7bf, w7t, b7, y7b, nullptr,
                                          B_C, GNN_C, GNN_C, 0);
  }
  postconv7_kernel<<<B_C, 256, 0, stream>>>(y7b, g7, bl7, node_idx, yx, x2bf);

  // post_mp + OOV + in_ln
  {
    dim3 g(B_C / 64, GNN_C / 64);
    mgemm64_kernel<<<g, 256, 0, stream>>>(x2bf, postWt, postb, nemb, nullptr,
                                          B_C, GNN_C, GNN_C, 0);
  }
  h0ln_kernel<<<B_C, 256, 0, stream>>>(nemb, node_idx, oov, ing, inb, h0lbf);

  // proj_in -> h fp32
  {
    dim3 g(B_C / 64, HID_C / 64);
    mgemm64_kernel<<<g, 256, 0, stream>>>(h0lbf, projWt, projb, h, nullptr,
                                          B_C, HID_C, GNN_C, 0);
  }
  lnbf_kernel<<<B_C, 256, 0, stream>>>(h, rbg, rbb, tbf);

  // residual blocks: W1(gelu) -> W2 split-K -> combine+LN(next)
  for (int i = 0; i < NBLK_C; ++i) {
    {
      dim3 g(B_C / 64, (4 * HID_C) / 64);
      mgemm64_kernel<<<g, 256, 0, stream>>>(tbf, rbW1t + (size_t)i * HID_C * 4 * HID_C,
                                            rbb1 + (size_t)i * 4 * HID_C, nullptr, ubf,
                                            B_C, 4 * HID_C, HID_C, 1);
    }
    {
      dim3 g(B_C / 64, HID_C / 64, 4);
      skmgemm64_kernel<<<g, 256, 0, stream>>>(ubf, rbW2t + (size_t)i * 4 * HID_C * HID_C,
                                              part, B_C, HID_C, 4 * HID_C, HID_C);
    }
    const float* gn = (i < NBLK_C - 1) ? rbg + (size_t)(i + 1) * HID_C : outg;
    const float* bn = (i < NBLK_C - 1) ? rbb + (size_t)(i + 1) * HID_C : outb;
    combln_kernel<<<B_C, 256, 0, stream>>>(part, h, rbb2 + (size_t)i * HID_C, gn, bn, tbf);
  }

  // bilinear -> pert bf16
  {
    dim3 g(B_C / 64, (NCLS_C * RANK_C) / 64);
    mgemm64_kernel<<<g, 256, 0, stream>>>(tbf, bilWt, bilb, nullptr, pertbf,
                                          B_C, NCLS_C * RANK_C, HID_C, 0);
  }

  // logits = pert[768,512] @ gene^T -> d_out fp32
  {
    dim3 g((B_C * NCLS_C) / 128, (NGENES_C + 127) / 128);
    mgemm_kernel<<<g, 256, 0, stream>>>(pertbf, genebf, nullptr, (float*)d_out,
                                        B_C * NCLS_C, NGENES_C, RANK_C);
  }
}

// Round 12
// 551.637 us; speedup vs baseline: 1.0774x; 1.0378x over previous
//
#include <hip/hip_runtime.h>
#include <hip/hip_bf16.h>
#include <cstdint>
#include <cstddef>

#define N_NODES_C 19385
#define N_EDGES_C 1200000
#define GNN_C 256
#define HID_C 512
#define RANK_C 512
#define NCLS_C 3
#define NGENES_C 6640
#define NBLK_C 6
#define B_C 256
#define LN_EPS 1e-5f

// private-histogram geometry: K blocks (one per CU), each owns ~E/K contiguous
// edges, 1024 threads (16 waves/CU) for latency hiding. Packed dual-16b LDS
// bins; per-half chunk count <= 4688 < 65536 and per-half cross-block prefix
// <= node in-degree (<65536) -> no overflow.
#define PH_K 256
#define PH_CHUNK ((N_EDGES_C + PH_K - 1) / PH_K)  // 4688
#define PH_NW ((N_NODES_C + 1) / 2)               // 9693 packed words (38.8 KB LDS)

typedef short bf8v __attribute__((ext_vector_type(8)));
typedef float f4v __attribute__((ext_vector_type(4)));
typedef int i2v __attribute__((ext_vector_type(2)));  // packed (src*GNN, bits(w))

__device__ __forceinline__ float bfu2f(unsigned short u) {
  union { unsigned int i; float f; } c; c.i = ((unsigned)u) << 16; return c.f;
}
__device__ __forceinline__ unsigned short f2bfu(float v) {
  union { float f; unsigned u; } c; c.f = v;
  unsigned r = c.u + 0x7FFFu + ((c.u >> 16) & 1u);
  return (unsigned short)(r >> 16);
}
__device__ __forceinline__ float gelu_tanh(float v) {
  const float x3 = v * v * v;
  return 0.5f * v * (1.f + tanhf(0.7978845608028654f * (v + 0.044715f * x3)));
}

// ---------------- batched fp32 -> bf16 convert ----------------

struct CvtSeg { const float* s; unsigned short* d; long long n; };
struct CvtArgs { CvtSeg seg[2]; int nseg; };

__global__ __launch_bounds__(256) void multicvt_kernel(CvtArgs a) {
  for (int sg = 0; sg < a.nseg; ++sg) {
    const float4* s = reinterpret_cast<const float4*>(a.seg[sg].s);
    unsigned short* d = a.seg[sg].d;
    const long long n4 = a.seg[sg].n >> 2;
    for (long long i = blockIdx.x * 256 + threadIdx.x; i < n4;
         i += (long long)gridDim.x * 256) {
      float4 v = s[i];
      ushort4 o;
      o.x = f2bfu(v.x); o.y = f2bfu(v.y); o.z = f2bfu(v.z); o.w = f2bfu(v.w);
      *reinterpret_cast<ushort4*>(d + i * 4) = o;
    }
  }
}

// ---------------- batched fp32 [R,C] -> bf16 transposed [C,R] ----------------

struct TSeg { const float* s; unsigned short* d; int R, C; };
struct TArgs { TSeg seg[12]; int nseg; };

__global__ __launch_bounds__(256) void multitrans_kernel(TArgs a) {
  __shared__ float tile[32][33];
  const int tx = threadIdx.x & 31;
  const int ty = threadIdx.x >> 5;  // 8 rows/pass
  for (int sg = 0; sg < a.nseg; ++sg) {
    const int R = a.seg[sg].R, C = a.seg[sg].C;
    const int tC = C >> 5;
    const int nt = (R >> 5) * tC;
    const float* src = a.seg[sg].s;
    unsigned short* dst = a.seg[sg].d;
    for (int tid = blockIdx.x; tid < nt; tid += gridDim.x) {
      const int tr = tid / tC, tc = tid - tr * tC;
      const int r0 = tr * 32, c0 = tc * 32;
      __syncthreads();
#pragma unroll
      for (int j = 0; j < 32; j += 8)
        tile[ty + j][tx] = src[(size_t)(r0 + ty + j) * C + c0 + tx];
      __syncthreads();
#pragma unroll
      for (int j = 0; j < 32; j += 8)
        dst[(size_t)(c0 + ty + j) * R + r0 + tx] = f2bfu(tile[tx][ty + j]);
    }
  }
}

// ---------------- frontier marking (fused zero+set: no memsets, no races) ----

__global__ __launch_bounds__(256) void initmark_kernel(const int* __restrict__ node_idx,
                                                       int* __restrict__ selbm,
                                                       int* __restrict__ needed) {
  __shared__ int sel[B_C];
  sel[threadIdx.x] = max(node_idx[threadIdx.x], 0);  // 256 threads == B_C
  __syncthreads();
  for (int i = blockIdx.x * 256 + threadIdx.x; i < N_NODES_C;
       i += gridDim.x * 256) {
    int m = 0;
#pragma unroll 16
    for (int j = 0; j < B_C; ++j) m |= (sel[j] == i);
    selbm[i] = m;
    needed[i] = m;
  }
}

// per-block private LDS histogram (packed 2x16b) + frontier source marking.
// ZERO global atomics: each block flushes its bins with plain coalesced stores.
__global__ __launch_bounds__(1024) void privhist_kernel(const int* __restrict__ src,
                                                        const int* __restrict__ dst,
                                                        const int* __restrict__ selbm,
                                                        int* __restrict__ needed,
                                                        unsigned int* __restrict__ cntp) {
  __shared__ unsigned int bins[PH_NW];
  const int t = threadIdx.x;
  for (int w = t; w < PH_NW; w += 1024) bins[w] = 0u;
  __syncthreads();
  const int base = blockIdx.x * PH_CHUNK;
  const int end = min(base + PH_CHUNK, N_EDGES_C);
#pragma unroll 2
  for (int i = base + t; i < end; i += 1024) {
    const int d = dst[i];
    atomicAdd(&bins[d >> 1], 1u << ((d & 1) * 16));
    if (selbm[d]) needed[src[i]] = 1;
  }
  __syncthreads();
  unsigned int* out = cntp + (size_t)blockIdx.x * PH_NW;
  for (int w = t; w < PH_NW; w += 1024) out[w] = bins[w];
}

// sum the PH_K packed private histograms -> per-node degree (int), and
// REPLACE cntp[k][w] in place with the packed EXCLUSIVE cross-block prefix.
__global__ __launch_bounds__(256) void redhist_kernel(unsigned int* __restrict__ cntp,
                                                      int* __restrict__ cnt) {
  const int w = blockIdx.x * 256 + threadIdx.x;
  if (w >= PH_NW) return;
  unsigned int lo = 0, hi = 0;
#pragma unroll 4
  for (int k = 0; k < PH_K; ++k) {
    const size_t idx = (size_t)k * PH_NW + w;
    const unsigned int u = cntp[idx];
    cntp[idx] = lo | (hi << 16);
    lo += u & 0xFFFFu;
    hi += u >> 16;
  }
  cnt[2 * w] = (int)lo;
  if (2 * w + 1 < N_NODES_C) cnt[2 * w + 1] = (int)hi;
}

__global__ __launch_bounds__(1024) void scan_kernel(const int* __restrict__ cnt,
                                                    int* __restrict__ off, int n) {
  __shared__ int sums[1024];
  const int t = threadIdx.x;
  const int CH = (n + 1023) >> 10;
  const int base = t * CH;
  int s = 0;
  for (int i = 0; i < CH; ++i) {
    int idx = base + i;
    if (idx < n) s += cnt[idx];
  }
  sums[t] = s;
  __syncthreads();
  for (int d = 1; d < 1024; d <<= 1) {
    int v = (t >= d) ? sums[t - d] : 0;
    __syncthreads();
    sums[t] += v;
    __syncthreads();
  }
  int run = (t == 0) ? 0 : sums[t - 1];
  for (int i = 0; i < CH; ++i) {
    int idx = base + i;
    if (idx < n) { off[idx] = run; run += cnt[idx]; }
  }
  if (t == 0) off[n] = sums[1023];
}

// deterministic-slot scatter, ZERO global atomics (prefix-seeded LDS ranks).
__global__ __launch_bounds__(1024) void fill_kernel(const int* __restrict__ src,
                                                    const int* __restrict__ dst,
                                                    const float* __restrict__ ew,
                                                    const int* __restrict__ off,
                                                    const unsigned int* __restrict__ cntp,
                                                    const int* __restrict__ needed,
                                                    i2v* __restrict__ ep) {
  __shared__ unsigned int bins[PH_NW];
  const int t = threadIdx.x;
  const unsigned int* myp = cntp + (size_t)blockIdx.x * PH_NW;
  for (int w = t; w < PH_NW; w += 1024) bins[w] = myp[w];
  __syncthreads();
  const int base = blockIdx.x * PH_CHUNK;
  const int end = min(base + PH_CHUNK, N_EDGES_C);
#pragma unroll 2
  for (int i = base + t; i < end; i += 1024) {
    const int d = dst[i];
    if (!needed[d]) continue;
    const int sh = (d & 1) * 16;
    const unsigned int old = atomicAdd(&bins[d >> 1], 1u << sh);
    const int rank = (int)((old >> sh) & 0xFFFFu);
    i2v e;
    e[0] = src[i] * GNN_C;
    e[1] = __float_as_int(ew[i]);
    ep[off[d] + rank] = e;
  }
}

// ---------------- edge aggregation ----------------

__global__ __launch_bounds__(256) void agg_full_kernel(const i2v* __restrict__ ep,
                                                       const int* __restrict__ off,
                                                       const int* __restrict__ needed,
                                                       const unsigned short* __restrict__ x,
                                                       unsigned short* __restrict__ aggbf) {
  const int n = blockIdx.x;
  if (!needed[n]) return;  // uniform: whole block exits together
  __shared__ f4v red[4][64];
  const int t = threadIdx.x;
  const int w = __builtin_amdgcn_readfirstlane(t >> 6);
  const int lane = t & 63;
  const int s0 = off[n];
  const int c = off[n + 1] - s0;
  const int q0 = s0 + ((c * w) >> 2);
  const int q1 = s0 + ((c * (w + 1)) >> 2);
  float a0 = 0.f, a1 = 0.f, a2 = 0.f, a3 = 0.f;
  const unsigned short* xl = x + 4 * lane;
#pragma unroll 4
  for (int p = q0; p < q1; ++p) {
    const i2v e = ep[p];  // wave-uniform -> s_load_dwordx2
    const int s = e[0];
    const float wg = __int_as_float(e[1]);
    const ushort4 v = *reinterpret_cast<const ushort4*>(xl + s);
    a0 = fmaf(bfu2f(v.x), wg, a0);
    a1 = fmaf(bfu2f(v.y), wg, a1);
    a2 = fmaf(bfu2f(v.z), wg, a2);
    a3 = fmaf(bfu2f(v.w), wg, a3);
  }
  f4v av; av[0] = a0; av[1] = a1; av[2] = a2; av[3] = a3;
  red[w][lane] = av;
  __syncthreads();
  const float* rf = reinterpret_cast<const float*>(red);
  const float sum = rf[t] + rf[256 + t] + rf[512 + t] + rf[768 + t];
  aggbf[(size_t)n * GNN_C + t] = f2bfu(sum);
}

__global__ __launch_bounds__(256) void agg_sel_kernel(const int* __restrict__ node_idx,
                                                      const i2v* __restrict__ ep,
                                                      const int* __restrict__ off,
                                                      const float* __restrict__ x,
                                                      unsigned short* __restrict__ aggbf) {
  __shared__ f4v red[4][64];
  const int b = blockIdx.x;
  const int t = threadIdx.x;
  const int n = max(node_idx[b], 0);
  const int w = __builtin_amdgcn_readfirstlane(t >> 6);
  const int lane = t & 63;
  const int s0 = off[n];
  const int c = off[n + 1] - s0;
  const int q0 = s0 + ((c * w) >> 2);
  const int q1 = s0 + ((c * (w + 1)) >> 2);
  float a0 = 0.f, a1 = 0.f, a2 = 0.f, a3 = 0.f;
  const float* xl = x + 4 * lane;
#pragma unroll 2
  for (int p = q0; p < q1; ++p) {
    const i2v e = ep[p];
    const int s = e[0];
    const float wg = __int_as_float(e[1]);
    const f4v v = *reinterpret_cast<const f4v*>(xl + s);
    a0 = fmaf(v[0], wg, a0);
    a1 = fmaf(v[1], wg, a1);
    a2 = fmaf(v[2], wg, a2);
    a3 = fmaf(v[3], wg, a3);
  }
  f4v av; av[0] = a0; av[1] = a1; av[2] = a2; av[3] = a3;
  red[w][lane] = av;
  __syncthreads();
  const float* rf = reinterpret_cast<const float*>(red);
  const float sum = rf[t] + rf[256 + t] + rf[512 + t] + rf[768 + t];
  aggbf[(size_t)b * GNN_C + t] = f2bfu(sum);
}

// ---------------- MFMA bf16 GEMM 128x128, transB only ----------------

#define MBK 32
#define MLDW 40

__global__ __launch_bounds__(256) void mgemm_kernel(const unsigned short* __restrict__ A,
                                                    const unsigned short* __restrict__ Bt,
                                                    const float* __restrict__ bias,
                                                    float* __restrict__ C,
                                                    int M, int N, int K) {
  __shared__ unsigned short As[128][MLDW];
  __shared__ unsigned short Bs[128][MLDW];
  const int t = threadIdx.x;
  const int lane = t & 63;
  const int wave = t >> 6;
  const int r0 = blockIdx.x * 128;
  const int c0 = blockIdx.y * 128;
  const int wm = (wave >> 1) * 64;
  const int wn = (wave & 1) * 64;
  const int lm = lane & 15;
  const int lq = lane >> 4;

  f4v acc[4][4];
  for (int i = 0; i < 4; ++i)
    for (int j = 0; j < 4; ++j)
      for (int r = 0; r < 4; ++r) acc[i][j][r] = 0.f;

  const int row = t >> 1;
  const int kof = (t & 1) * 16;
  for (int k0 = 0; k0 < K; k0 += MBK) {
    {
      const int gr = r0 + row;
      uint4 u0 = make_uint4(0, 0, 0, 0), u1 = u0;
      if (gr < M) {
        const uint4* p = reinterpret_cast<const uint4*>(A + (size_t)gr * K + k0 + kof);
        u0 = p[0]; u1 = p[1];
      }
      *reinterpret_cast<uint4*>(&As[row][kof]) = u0;
      *reinterpret_cast<uint4*>(&As[row][kof + 8]) = u1;
    }
    {
      const int gn = c0 + row;
      uint4 u0 = make_uint4(0, 0, 0, 0), u1 = u0;
      if (gn < N) {
        const uint4* p = reinterpret_cast<const uint4*>(Bt + (size_t)gn * K + k0 + kof);
        u0 = p[0]; u1 = p[1];
      }
      *reinterpret_cast<uint4*>(&Bs[row][kof]) = u0;
      *reinterpret_cast<uint4*>(&Bs[row][kof + 8]) = u1;
    }
    __syncthreads();

    bf8v a[4], b[4];
#pragma unroll
    for (int i = 0; i < 4; ++i)
      a[i] = *reinterpret_cast<const bf8v*>(&As[wm + i * 16 + lm][lq * 8]);
#pragma unroll
    for (int j = 0; j < 4; ++j)
      b[j] = *reinterpret_cast<const bf8v*>(&Bs[wn + j * 16 + lm][lq * 8]);
#pragma unroll
    for (int i = 0; i < 4; ++i)
#pragma unroll
      for (int j = 0; j < 4; ++j)
        acc[i][j] = __builtin_amdgcn_mfma_f32_16x16x32_bf16(a[i], b[j], acc[i][j], 0, 0, 0);
    __syncthreads();
  }

  for (int ti = 0; ti < 4; ++ti) {
    for (int tj = 0; tj < 4; ++tj) {
      const int col = c0 + wn + tj * 16 + lm;
      if (col >= N) continue;
      const float bv = bias ? bias[col] : 0.f;
      for (int r = 0; r < 4; ++r) {
        const int row2 = r0 + wm + ti * 16 + lq * 4 + r;
        if (row2 < M) C[(size_t)row2 * N + col] = acc[ti][tj][r] + bv;
      }
    }
  }
}

// ---------------- MFMA bf16 GEMM 32x64 tiles, transB, fused epilogue ----------------
// 256 thr / 4 waves; wave w owns cols [w*16, w*16+16) of a 32x64 tile.
// Dims must be multiples of 32 (M) / 64 (N) / 32 (K) -- true for all head calls.
// High block count -> multiple blocks/CU for the small latency-bound head GEMMs.

__global__ __launch_bounds__(256) void mgemm32_kernel(const unsigned short* __restrict__ A,
                                                      const unsigned short* __restrict__ Bt,
                                                      const float* __restrict__ bias,
                                                      float* outF, unsigned short* outB,
                                                      int M, int N, int K, int doGelu) {
  __shared__ unsigned short As[32][MLDW];
  __shared__ unsigned short Bs[64][MLDW];
  const int t = threadIdx.x;
  const int lane = t & 63;
  const int wave = t >> 6;  // 0..3
  const int r0 = blockIdx.x * 32;
  const int c0 = blockIdx.y * 64;
  const int wn = wave * 16;
  const int lm = lane & 15;
  const int lq = lane >> 4;

  f4v acc[2];
#pragma unroll
  for (int i = 0; i < 2; ++i)
#pragma unroll
    for (int r = 0; r < 4; ++r) acc[i][r] = 0.f;

  const int arow = t >> 3, akof = (t & 7) * 4;  // 32 rows x 32k = 256 x ushort4
  const int brow = t >> 2, bkof = (t & 3) * 8;  // 64 rows x 32k = 256 x uint4
  for (int k0 = 0; k0 < K; k0 += MBK) {
    *reinterpret_cast<ushort4*>(&As[arow][akof]) =
        *reinterpret_cast<const ushort4*>(A + (size_t)(r0 + arow) * K + k0 + akof);
    *reinterpret_cast<uint4*>(&Bs[brow][bkof]) =
        *reinterpret_cast<const uint4*>(Bt + (size_t)(c0 + brow) * K + k0 + bkof);
    __syncthreads();
    bf8v a[2], b;
#pragma unroll
    for (int i = 0; i < 2; ++i)
      a[i] = *reinterpret_cast<const bf8v*>(&As[i * 16 + lm][lq * 8]);
    b = *reinterpret_cast<const bf8v*>(&Bs[wn + lm][lq * 8]);
#pragma unroll
    for (int i = 0; i < 2; ++i)
      acc[i] = __builtin_amdgcn_mfma_f32_16x16x32_bf16(a[i], b, acc[i], 0, 0, 0);
    __syncthreads();
  }

  const int col = c0 + wn + lm;
  const float bv = bias ? bias[col] : 0.f;
#pragma unroll
  for (int ti = 0; ti < 2; ++ti)
#pragma unroll
    for (int r = 0; r < 4; ++r) {
      const int row2 = r0 + ti * 16 + lq * 4 + r;
      float v = acc[ti][r] + bv;
      if (doGelu) v = gelu_tanh(v);
      if (outF) outF[(size_t)row2 * N + col] = v;
      else outB[(size_t)row2 * N + col] = f2bfu(v);
    }
}

// split-K variant: grid.z slices write raw fp32 partials part[z][M][N]
__global__ __launch_bounds__(256) void skmgemm32_kernel(const unsigned short* __restrict__ A,
                                                        const unsigned short* __restrict__ Bt,
                                                        float* __restrict__ part,
                                                        int M, int N, int K, int kc) {
  __shared__ unsigned short As[32][MLDW];
  __shared__ unsigned short Bs[64][MLDW];
  const int t = threadIdx.x;
  const int lane = t & 63;
  const int wave = t >> 6;
  const int r0 = blockIdx.x * 32;
  const int c0 = blockIdx.y * 64;
  const int kBeg = blockIdx.z * kc;
  const int kEnd = kBeg + kc;
  const int wn = wave * 16;
  const int lm = lane & 15;
  const int lq = lane >> 4;

  f4v acc[2];
#pragma unroll
  for (int i = 0; i < 2; ++i)
#pragma unroll
    for (int r = 0; r < 4; ++r) acc[i][r] = 0.f;

  const int arow = t >> 3, akof = (t & 7) * 4;
  const int brow = t >> 2, bkof = (t & 3) * 8;
  for (int k0 = kBeg; k0 < kEnd; k0 += MBK) {
    *reinterpret_cast<ushort4*>(&As[arow][akof]) =
        *reinterpret_cast<const ushort4*>(A + (size_t)(r0 + arow) * K + k0 + akof);
    *reinterpret_cast<uint4*>(&Bs[brow][bkof]) =
        *reinterpret_cast<const uint4*>(Bt + (size_t)(c0 + brow) * K + k0 + bkof);
    __syncthreads();
    bf8v a[2], b;
#pragma unroll
    for (int i = 0; i < 2; ++i)
      a[i] = *reinterpret_cast<const bf8v*>(&As[i * 16 + lm][lq * 8]);
    b = *reinterpret_cast<const bf8v*>(&Bs[wn + lm][lq * 8]);
#pragma unroll
    for (int i = 0; i < 2; ++i)
      acc[i] = __builtin_amdgcn_mfma_f32_16x16x32_bf16(a[i], b, acc[i], 0, 0, 0);
    __syncthreads();
  }

  float* out = part + (size_t)blockIdx.z * M * N;
  const int col = c0 + wn + lm;
#pragma unroll
  for (int ti = 0; ti < 2; ++ti)
#pragma unroll
    for (int r = 0; r < 4; ++r) {
      const int row2 = r0 + ti * 16 + lq * 4 + r;
      out[(size_t)row2 * N + col] = acc[ti][r];
    }
}

// ---------------- fused conv6 GEMM + LayerNorm (v2: 32-row blocks) ----------------
// 32-row x 256-col blocks, 8 waves (512 thr); wave w owns cols [w*32,(w+1)*32).
// 606 blocks (~2.4/CU) so staging/barrier stalls overlap across blocks.
// B-staging: one uint4 (8 shorts) per id at row id>>2, kof (id&3)*8 -> full
// 256x32 coverage (1024 ids x 8 shorts = 8192), 16B-aligned (row stride 80B).
// conv6: yx[row] = frozen[row] + relu(LN(agg@W6 + b6)) for needed rows only.
__global__ __launch_bounds__(512) void gemmln6_kernel(const unsigned short* __restrict__ A,
                                                      const unsigned short* __restrict__ Bt,
                                                      const float* __restrict__ bias,
                                                      const float* __restrict__ g,
                                                      const float* __restrict__ b,
                                                      const float* __restrict__ frozen,
                                                      const int* __restrict__ needed,
                                                      float* __restrict__ yx, int M) {
  __shared__ unsigned short As[32][MLDW];
  __shared__ unsigned short Bs[256][MLDW];
  __shared__ float rs[32][8];
  const int t = threadIdx.x;
  const int lane = t & 63;
  const int wave = t >> 6;  // 0..7
  const int r0 = blockIdx.x * 32;
  const int lm = lane & 15, lq = lane >> 4;

  f4v acc[2][2];
#pragma unroll
  for (int i = 0; i < 2; ++i)
#pragma unroll
    for (int j = 0; j < 2; ++j)
#pragma unroll
      for (int r = 0; r < 4; ++r) acc[i][j][r] = 0.f;

  const int arow = t >> 3, akof = (t & 7) * 4;  // t<256: 32 rows x 32k ushort4
  for (int k0 = 0; k0 < GNN_C; k0 += MBK) {
    if (t < 256) {
      ushort4 u = make_ushort4(0, 0, 0, 0);
      const int gr = r0 + arow;
      if (gr < M) u = *reinterpret_cast<const ushort4*>(A + (size_t)gr * GNN_C + k0 + akof);
      *reinterpret_cast<ushort4*>(&As[arow][akof]) = u;
    }
#pragma unroll
    for (int j = 0; j < 2; ++j) {
      const int id = t + 512 * j;
      const int brow = id >> 2, bkof = (id & 3) * 8;
      *reinterpret_cast<uint4*>(&Bs[brow][bkof]) =
          *reinterpret_cast<const uint4*>(Bt + (size_t)brow * GNN_C + k0 + bkof);
    }
    __syncthreads();
    bf8v a[2], bf[2];
#pragma unroll
    for (int ti = 0; ti < 2; ++ti)
      a[ti] = *reinterpret_cast<const bf8v*>(&As[ti * 16 + lm][lq * 8]);
#pragma unroll
    for (int tj = 0; tj < 2; ++tj)
      bf[tj] = *reinterpret_cast<const bf8v*>(&Bs[wave * 32 + tj * 16 + lm][lq * 8]);
#pragma unroll
    for (int ti = 0; ti < 2; ++ti)
#pragma unroll
      for (int tj = 0; tj < 2; ++tj)
        acc[ti][tj] = __builtin_amdgcn_mfma_f32_16x16x32_bf16(a[ti], bf[tj], acc[ti][tj], 0, 0, 0);
    __syncthreads();
  }

  // + bias (pre-LN, matches reference y6 = agg@W + b)
  const int c0 = wave * 32 + lm, c1 = c0 + 16;
  const float b0 = bias[c0], b1 = bias[c1];
#pragma unroll
  for (int ti = 0; ti < 2; ++ti)
#pragma unroll
    for (int r = 0; r < 4; ++r) { acc[ti][0][r] += b0; acc[ti][1][r] += b1; }

  // mean
  float m[2][4];
#pragma unroll
  for (int ti = 0; ti < 2; ++ti)
#pragma unroll
    for (int r = 0; r < 4; ++r) {
      float s = acc[ti][0][r] + acc[ti][1][r];
      for (int o = 1; o < 16; o <<= 1) s += __shfl_xor(s, o, 64);
      if (lm == 0) rs[ti * 16 + lq * 4 + r][wave] = s;
    }
  __syncthreads();
#pragma unroll
  for (int ti = 0; ti < 2; ++ti)
#pragma unroll
    for (int r = 0; r < 4; ++r) {
      const int row = ti * 16 + lq * 4 + r;
      float s = 0.f;
#pragma unroll
      for (int w2 = 0; w2 < 8; ++w2) s += rs[row][w2];
      m[ti][r] = s * (1.f / GNN_C);
    }
  __syncthreads();
  // variance
  float iv[2][4];
#pragma unroll
  for (int ti = 0; ti < 2; ++ti)
#pragma unroll
    for (int r = 0; r < 4; ++r) {
      const float d0 = acc[ti][0][r] - m[ti][r];
      const float d1 = acc[ti][1][r] - m[ti][r];
      float s = d0 * d0 + d1 * d1;
      for (int o = 1; o < 16; o <<= 1) s += __shfl_xor(s, o, 64);
      if (lm == 0) rs[ti * 16 + lq * 4 + r][wave] = s;
    }
  __syncthreads();
#pragma unroll
  for (int ti = 0; ti < 2; ++ti)
#pragma unroll
    for (int r = 0; r < 4; ++r) {
      const int row = ti * 16 + lq * 4 + r;
      float s = 0.f;
#pragma unroll
      for (int w2 = 0; w2 < 8; ++w2) s += rs[row][w2];
      iv[ti][r] = rsqrtf(s * (1.f / GNN_C) + LN_EPS);
    }

  const float g0 = g[c0], g1 = g[c1], bb0 = b[c0], bb1 = b[c1];
#pragma unroll
  for (int ti = 0; ti < 2; ++ti)
#pragma unroll
    for (int r = 0; r < 4; ++r) {
      const int grow = r0 + ti * 16 + lq * 4 + r;
      if (grow < M && needed[grow]) {
        const size_t base = (size_t)grow * GNN_C;
        const float x0 = fmaxf((acc[ti][0][r] - m[ti][r]) * iv[ti][r] * g0 + bb0, 0.f);
        const float x1 = fmaxf((acc[ti][1][r] - m[ti][r]) * iv[ti][r] * g1 + bb1, 0.f);
        yx[base + c0] = frozen[base + c0] + x0;
        yx[base + c1] = frozen[base + c1] + x1;
      }
    }
}

// ---------------- LN family (head path) ----------------

__global__ __launch_bounds__(256) void postconv7_kernel(const float* __restrict__ y,
                                                        const float* __restrict__ g,
                                                        const float* __restrict__ b,
                                                        const int* __restrict__ idx,
                                                        const float* __restrict__ x1f,
                                                        unsigned short* __restrict__ out) {
  __shared__ float sb[4];
  const int bi = blockIdx.x, t = threadIdx.x;
  const int n = max(idx[bi], 0);
  const float v = y[(size_t)bi * GNN_C + t];
  float s = v;
  for (int o = 32; o; o >>= 1) s += __shfl_down(s, o, 64);
  if ((t & 63) == 0) sb[t >> 6] = s;
  __syncthreads();
  const float m = (sb[0] + sb[1] + sb[2] + sb[3]) * (1.f / GNN_C);
  __syncthreads();
  const float d = v - m;
  s = d * d;
  for (int o = 32; o; o >>= 1) s += __shfl_down(s, o, 64);
  if ((t & 63) == 0) sb[t >> 6] = s;
  __syncthreads();
  const float rs = rsqrtf((sb[0] + sb[1] + sb[2] + sb[3]) * (1.f / GNN_C) + LN_EPS);
  const float xn = d * rs * g[t] + b[t];
  out[(size_t)bi * GNN_C + t] = f2bfu(x1f[(size_t)n * GNN_C + t] + fmaxf(xn, 0.f));
}

__global__ __launch_bounds__(256) void h0ln_kernel(const float* __restrict__ ne,
                                                   const int* __restrict__ idx,
                                                   const float* __restrict__ oov,
                                                   const float* __restrict__ g,
                                                   const float* __restrict__ b,
                                                   unsigned short* __restrict__ out) {
  __shared__ float sb[4];
  const int bi = blockIdx.x, t = threadIdx.x;
  const float v = (idx[bi] >= 0) ? ne[(size_t)bi * GNN_C + t] : oov[t];
  float s = v;
  for (int o = 32; o; o >>= 1) s += __shfl_down(s, o, 64);
  if ((t & 63) == 0) sb[t >> 6] = s;
  __syncthreads();
  const float m = (sb[0] + sb[1] + sb[2] + sb[3]) * (1.f / GNN_C);
  __syncthreads();
  const float d = v - m;
  s = d * d;
  for (int o = 32; o; o >>= 1) s += __shfl_down(s, o, 64);
  if ((t & 63) == 0) sb[t >> 6] = s;
  __syncthreads();
  const float rs = rsqrtf((sb[0] + sb[1] + sb[2] + sb[3]) * (1.f / GNN_C) + LN_EPS);
  out[(size_t)bi * GNN_C + t] = f2bfu(d * rs * g[t] + b[t]);
}

// plain LN over 512-rows of h -> bf16
__global__ __launch_bounds__(256) void lnbf_kernel(const float* __restrict__ in,
                                                   const float* __restrict__ g,
                                                   const float* __restrict__ b,
                                                   unsigned short* __restrict__ out) {
  __shared__ float sb[4];
  const int r = blockIdx.x, t = threadIdx.x;
  const float v0 = in[(size_t)r * HID_C + t];
  const float v1 = in[(size_t)r * HID_C + t + 256];
  float s = v0 + v1;
  for (int o = 32; o; o >>= 1) s += __shfl_down(s, o, 64);
  if ((t & 63) == 0) sb[t >> 6] = s;
  __syncthreads();
  const float m = (sb[0] + sb[1] + sb[2] + sb[3]) * (1.f / HID_C);
  __syncthreads();
  const float d0 = v0 - m, d1 = v1 - m;
  s = d0 * d0 + d1 * d1;
  for (int o = 32; o; o >>= 1) s += __shfl_down(s, o, 64);
  if ((t & 63) == 0) sb[t >> 6] = s;
  __syncthreads();
  const float rs = rsqrtf((sb[0] + sb[1] + sb[2] + sb[3]) * (1.f / HID_C) + LN_EPS);
  out[(size_t)r * HID_C + t] = f2bfu(d0 * rs * g[t] + b[t]);
  out[(size_t)r * HID_C + t + 256] = f2bfu(d1 * rs * g[t + 256] + b[t + 256]);
}

// combine split-K partials + bias + residual into h, then LN (next gamma/beta) -> bf16
__global__ __launch_bounds__(256) void combln_kernel(const float* __restrict__ part,
                                                     float* __restrict__ h,
                                                     const float* __restrict__ b2,
                                                     const float* __restrict__ g,
                                                     const float* __restrict__ b,
                                                     unsigned short* __restrict__ out) {
  __shared__ float sb[4];
  const int r = blockIdx.x, t = threadIdx.x;
  const int MN = B_C * HID_C;
  const size_t o0 = (size_t)r * HID_C + t;
  const size_t o1 = o0 + 256;
  float v0 = h[o0] + b2[t] + part[o0] + part[MN + o0] + part[2 * MN + o0] + part[3 * MN + o0];
  float v1 = h[o1] + b2[t + 256] + part[o1] + part[MN + o1] + part[2 * MN + o1] + part[3 * MN + o1];
  h[o0] = v0;
  h[o1] = v1;
  float s = v0 + v1;
  for (int o = 32; o; o >>= 1) s += __shfl_down(s, o, 64);
  if ((t & 63) == 0) sb[t >> 6] = s;
  __syncthreads();
  const float m = (sb[0] + sb[1] + sb[2] + sb[3]) * (1.f / HID_C);
  __syncthreads();
  const float d0 = v0 - m, d1 = v1 - m;
  s = d0 * d0 + d1 * d1;
  for (int o = 32; o; o >>= 1) s += __shfl_down(s, o, 64);
  if ((t & 63) == 0) sb[t >> 6] = s;
  __syncthreads();
  const float rsq = rsqrtf((sb[0] + sb[1] + sb[2] + sb[3]) * (1.f / HID_C) + LN_EPS);
  out[o0] = f2bfu(d0 * rsq * g[t] + b[t]);
  out[o1] = f2bfu(d1 * rsq * g[t + 256] + b[t + 256]);
}

// ---------------- host ----------------

extern "C" void kernel_launch(void* const* d_in, const int* in_sizes, int n_in,
                              void* d_out, int out_size, void* d_ws, size_t ws_size,
                              hipStream_t stream) {
  const int* node_idx = (const int*)d_in[0];
  const int* e_src = (const int*)d_in[1];
  const int* e_dst = e_src + N_EDGES_C;
  const float* ew = (const float*)d_in[2];
  const float* frozen = (const float*)d_in[3];
  const float* W6 = (const float*)d_in[4];
  const float* b6 = (const float*)d_in[5];
  const float* g6 = (const float*)d_in[6];
  const float* bl6 = (const float*)d_in[7];
  const float* W7 = (const float*)d_in[8];
  const float* b7 = (const float*)d_in[9];
  const float* g7 = (const float*)d_in[10];
  const float* bl7 = (const float*)d_in[11];
  const float* postW = (const float*)d_in[12];
  const float* postb = (const float*)d_in[13];
  const float* oov = (const float*)d_in[14];
  const float* ing = (const float*)d_in[15];
  const float* inb = (const float*)d_in[16];
  const float* projW = (const float*)d_in[17];
  const float* projb = (const float*)d_in[18];
  const float* rbg = (const float*)d_in[19];
  const float* rbb = (const float*)d_in[20];
  const float* rbW1 = (const float*)d_in[21];
  const float* rbb1 = (const float*)d_in[22];
  const float* rbW2 = (const float*)d_in[23];
  const float* rbb2 = (const float*)d_in[24];
  const float* outg = (const float*)d_in[25];
  const float* outb = (const float*)d_in[26];
  const float* bilW = (const float*)d_in[27];
  const float* bilb = (const float*)d_in[28];
  const float* gene = (const float*)d_in[29];
  (void)in_sizes; (void)n_in; (void)out_size; (void)ws_size;

  char* ws = (char*)d_ws;
  size_t o = 0;
  auto alloc = [&](size_t bytes) -> char* {
    char* p = ws + o;
    o += (bytes + 255) & ~(size_t)255;
    return p;
  };
  int* cnt = (int*)alloc((size_t)N_NODES_C * 4);
  int* off = (int*)alloc((size_t)(N_NODES_C + 1) * 4);
  int* needed = (int*)alloc((size_t)N_NODES_C * 4);
  int* selbm = (int*)alloc((size_t)N_NODES_C * 4);
  unsigned int* cntp = (unsigned int*)alloc((size_t)PH_K * PH_NW * 4);
  i2v* ep = (i2v*)alloc((size_t)N_EDGES_C * 8);
  unsigned short* frozbf = (unsigned short*)alloc((size_t)N_NODES_C * GNN_C * 2);
  // aggregion: agg6bf (9.93 MB, dead after conv6 GEMM) then rbW1t (12.58 MB, phase B)
  char* aggregion = alloc((size_t)NBLK_C * HID_C * 4 * HID_C * 2);
  unsigned short* w6t = (unsigned short*)alloc((size_t)GNN_C * GNN_C * 2);
  unsigned short* w7t = (unsigned short*)alloc((size_t)GNN_C * GNN_C * 2);
  unsigned short* postWt = (unsigned short*)alloc((size_t)GNN_C * GNN_C * 2);
  unsigned short* projWt = (unsigned short*)alloc((size_t)HID_C * GNN_C * 2);
  unsigned short* bilWt = (unsigned short*)alloc((size_t)NCLS_C * RANK_C * HID_C * 2);
  float* yx = (float*)alloc((size_t)N_NODES_C * GNN_C * 4);  // x1 fp32 (gated write)
  unsigned short* rbW2t = (unsigned short*)alloc((size_t)NBLK_C * 4 * HID_C * HID_C * 2);
  float* part = (float*)alloc((size_t)4 * B_C * HID_C * 4);
  unsigned short* agg7bf = (unsigned short*)alloc((size_t)B_C * GNN_C * 2);
  float* y7b = (float*)alloc((size_t)B_C * GNN_C * 4);
  unsigned short* x2bf = (unsigned short*)alloc((size_t)B_C * GNN_C * 2);
  float* nemb = (float*)alloc((size_t)B_C * GNN_C * 4);
  unsigned short* h0lbf = (unsigned short*)alloc((size_t)B_C * GNN_C * 2);
  float* h = (float*)alloc((size_t)B_C * HID_C * 4);
  unsigned short* tbf = (unsigned short*)alloc((size_t)B_C * HID_C * 2);
  unsigned short* ubf = (unsigned short*)alloc((size_t)B_C * 4 * HID_C * 2);
  unsigned short* pertbf = (unsigned short*)alloc((size_t)B_C * NCLS_C * RANK_C * 2);

  unsigned short* agg6bf = (unsigned short*)aggregion;
  unsigned short* rbW1t = (unsigned short*)aggregion;
  unsigned short* genebf = frozbf;  // frozbf dead after agg_full

  // frontier marking (fused zero+set) + privatized histogram + prefix
  // write-back, then deterministic-slot fill (zero global atomics)
  initmark_kernel<<<80, 256, 0, stream>>>(node_idx, selbm, needed);
  privhist_kernel<<<PH_K, 1024, 0, stream>>>(e_src, e_dst, selbm, needed, cntp);
  redhist_kernel<<<(PH_NW + 255) / 256, 256, 0, stream>>>(cntp, cnt);
  scan_kernel<<<1, 1024, 0, stream>>>(cnt, off, N_NODES_C);
  fill_kernel<<<PH_K, 1024, 0, stream>>>(e_src, e_dst, ew, off, cntp, needed, ep);

  // phase A: frozen convert + small weight transposes
  {
    CvtArgs a;
    a.seg[0] = {frozen, frozbf, (long long)N_NODES_C * GNN_C};
    a.nseg = 1;
    multicvt_kernel<<<512, 256, 0, stream>>>(a);
  }
  {
    TArgs a;
    a.seg[0] = {W6, w6t, GNN_C, GNN_C};
    a.seg[1] = {W7, w7t, GNN_C, GNN_C};
    a.seg[2] = {postW, postWt, GNN_C, GNN_C};
    a.seg[3] = {projW, projWt, GNN_C, HID_C};
    a.seg[4] = {bilW, bilWt, HID_C, NCLS_C * RANK_C};
    a.nseg = 5;
    multitrans_kernel<<<512, 256, 0, stream>>>(a);
  }

  // conv6 trunk: aggregate then fused GEMM + LN + ReLU + residual (gated, 32-row blocks)
  agg_full_kernel<<<N_NODES_C, 256, 0, stream>>>(ep, off, needed, frozbf, agg6bf);
  gemmln6_kernel<<<(N_NODES_C + 31) / 32, 512, 0, stream>>>(agg6bf, w6t, b6, g6, bl6,
                                                            frozen, needed, yx, N_NODES_C);
  // yx = x1 fp32; agg6bf + frozbf dead

  // phase B: rb weight transposes (into aggregion + rbW2t) + gene convert
  {
    TArgs a;
    for (int i = 0; i < NBLK_C; ++i) {
      a.seg[i] = {rbW1 + (size_t)i * HID_C * 4 * HID_C,
                  rbW1t + (size_t)i * HID_C * 4 * HID_C, HID_C, 4 * HID_C};
      a.seg[6 + i] = {rbW2 + (size_t)i * 4 * HID_C * HID_C,
                      rbW2t + (size_t)i * 4 * HID_C * HID_C, 4 * HID_C, HID_C};
    }
    a.nseg = 12;
    multitrans_kernel<<<2048, 256, 0, stream>>>(a);
  }
  {
    CvtArgs a;
    a.seg[0] = {gene, genebf, (long long)NGENES_C * RANK_C};
    a.nseg = 1;
    multicvt_kernel<<<512, 256, 0, stream>>>(a);
  }

  // head: conv7 (32x64-tile GEMMs for CU coverage)
  agg_sel_kernel<<<B_C, 256, 0, stream>>>(node_idx, ep, off, yx, agg7bf);
  {
    dim3 g(B_C / 32, GNN_C / 64);
    mgemm32_kernel<<<g, 256, 0, stream>>>(agg7bf, w7t, b7, y7b, nullptr,
                                          B_C, GNN_C, GNN_C, 0);
  }
  postconv7_kernel<<<B_C, 256, 0, stream>>>(y7b, g7, bl7, node_idx, yx, x2bf);

  // post_mp + OOV + in_ln
  {
    dim3 g(B_C / 32, GNN_C / 64);
    mgemm32_kernel<<<g, 256, 0, stream>>>(x2bf, postWt, postb, nemb, nullptr,
                                          B_C, GNN_C, GNN_C, 0);
  }
  h0ln_kernel<<<B_C, 256, 0, stream>>>(nemb, node_idx, oov, ing, inb, h0lbf);

  // proj_in -> h fp32
  {
    dim3 g(B_C / 32, HID_C / 64);
    mgemm32_kernel<<<g, 256, 0, stream>>>(h0lbf, projWt, projb, h, nullptr,
                                          B_C, HID_C, GNN_C, 0);
  }
  lnbf_kernel<<<B_C, 256, 0, stream>>>(h, rbg, rbb, tbf);

  // residual blocks: W1(gelu) -> W2 split-K -> combine+LN(next)
  for (int i = 0; i < NBLK_C; ++i) {
    {
      dim3 g(B_C / 32, (4 * HID_C) / 64);
      mgemm32_kernel<<<g, 256, 0, stream>>>(tbf, rbW1t + (size_t)i * HID_C * 4 * HID_C,
                                            rbb1 + (size_t)i * 4 * HID_C, nullptr, ubf,
                                            B_C, 4 * HID_C, HID_C, 1);
    }
    {
      dim3 g(B_C / 32, HID_C / 64, 4);
      skmgemm32_kernel<<<g, 256, 0, stream>>>(ubf, rbW2t + (size_t)i * 4 * HID_C * HID_C,
                                              part, B_C, HID_C, 4 * HID_C, HID_C);
    }
    const float* gn = (i < NBLK_C - 1) ? rbg + (size_t)(i + 1) * HID_C : outg;
    const float* bn = (i < NBLK_C - 1) ? rbb + (size_t)(i + 1) * HID_C : outb;
    combln_kernel<<<B_C, 256, 0, stream>>>(part, h, rbb2 + (size_t)i * HID_C, gn, bn, tbf);
  }

  // bilinear -> pert bf16
  {
    dim3 g(B_C / 32, (NCLS_C * RANK_C) / 64);
    mgemm32_kernel<<<g, 256, 0, stream>>>(tbf, bilWt, bilb, nullptr, pertbf,
                                          B_C, NCLS_C * RANK_C, HID_C, 0);
  }

  // logits = pert[768,512] @ gene^T -> d_out fp32
  {
    dim3 g((B_C * NCLS_C) / 128, (NGENES_C + 127) / 128);
    mgemm_kernel<<<g, 256, 0, stream>>>(pertbf, genebf, nullptr, (float*)d_out,
                                        B_C * NCLS_C, NGENES_C, RANK_C);
  }
}